// Round 4
// baseline (806.560 us; speedup 1.0000x reference)
//
#include <hip/hip_runtime.h>
#include <math.h>

typedef __attribute__((ext_vector_type(8))) short bf16x8;
typedef __attribute__((ext_vector_type(4))) float f32x4;
typedef __attribute__((ext_vector_type(4))) short s16x4;

#define NBATCH 4
#define NPTS   4096
#define NTOT   (NBATCH*NPTS)   // 16384

__device__ __forceinline__ float bf2f(unsigned short h){
  unsigned int u = ((unsigned int)h) << 16;
  return __builtin_bit_cast(float, u);
}
__device__ __forceinline__ unsigned short f2bf(float f){
  unsigned int u = __builtin_bit_cast(unsigned int, f);
  u += 0x7FFFu + ((u >> 16) & 1u);   // RNE
  return (unsigned short)(u >> 16);
}

// byte offset into a [row][256 bf16] LDS tile (512B row stride), XOR-swizzled
__device__ __forceinline__ unsigned int swz(int row, int kbyte){
  return (unsigned int)(row * 512) + (((unsigned int)kbyte) ^ (((unsigned int)row & 7u) << 4));
}

#define MFMA(a,b,c) __builtin_amdgcn_mfma_f32_16x16x32_bf16((a),(b),(c),0,0,0)

// ---------------- prep: features -> bf16 ----------------
__global__ __launch_bounds__(256) void k_convert(const float* __restrict__ x,
                                                 unsigned short* __restrict__ xb, int n){
  int i = (blockIdx.x * 256 + threadIdx.x) * 4;
  if (i < n){
    float4 v = *(const float4*)(x + i);
    s16x4 o;
    o[0] = (short)f2bf(v.x); o[1] = (short)f2bf(v.y);
    o[2] = (short)f2bf(v.z); o[3] = (short)f2bf(v.w);
    *(s16x4*)(xb + i) = o;
  }
}

// ---------------- prep: transposed bf16 weight copies ----------------
__global__ __launch_bounds__(256) void k_prep_mats(
    const float* __restrict__ scw, const float* __restrict__ g2,
    const float* __restrict__ fc2, const float* __restrict__ W2,
    const float* __restrict__ scb,
    unsigned short* __restrict__ qkv2T, unsigned short* __restrict__ g2sT,
    unsigned short* __restrict__ fc2T, unsigned short* __restrict__ BposT,
    float* __restrict__ cvec){
  int c = blockIdx.x, d = threadIdx.x;
  qkv2T[(768+c)*256 + d] = f2bf(scw[d*256 + c]);             // sc^T
  g2sT[c*256 + d]        = f2bf(g2[d*256 + c] * 0.0625f);    // fold 1/sqrt(DM)=1/16
  fc2T[c*256 + d]        = f2bf(fc2[d*256 + c]);
  BposT[(256+c)*256 + d] = f2bf(W2[d*256 + c]);              // W2^T (pe)
  if (d == 0) cvec[768 + c] = scb[c];
}

// ---------------- prep stage 1: Wqg = wq@g1, Wkg = wk@g1, W2g1, c1 ----------------
__global__ __launch_bounds__(256) void k_prep_gemm(
    const float* __restrict__ wq, const float* __restrict__ wk,
    const float* __restrict__ g1, const float* __restrict__ W2,
    const float* __restrict__ b2d, const float* __restrict__ gb1,
    unsigned short* __restrict__ tmpWq, unsigned short* __restrict__ tmpWk,
    unsigned short* __restrict__ BposT, float* __restrict__ c1){
  int c = threadIdx.x, bid = blockIdx.x;
  if (bid < 256){                       // tmpWq[c][e... row c = (wq@g1)^T row c]
    int d = bid; float acc = 0.f;
    for (int e=0;e<256;e++) acc += wq[d*256+e]*g1[e*256+c];
    tmpWq[c*256 + d] = f2bf(acc);
  } else if (bid < 512){
    int d = bid-256; float acc = 0.f;
    for (int e=0;e<256;e++) acc += wk[d*256+e]*g1[e*256+c];
    tmpWk[c*256 + d] = f2bf(acc);
  } else if (bid < 768){                // W2g1^T -> BposT rows 0..255
    int d = bid-512; float acc = 0.f;
    for (int e=0;e<256;e++) acc += W2[d*256+e]*g1[e*256+c];
    BposT[c*256 + d] = f2bf(acc);
  } else {                              // c1 = b2d @ g1 + gb1
    float acc = 0.f;
    for (int e=0;e<256;e++) acc += b2d[e]*g1[e*256+c];
    c1[c] = acc + gb1[c];
  }
}

// ---------------- prep stage 2: fold fc1 into QKV: Fq=fc1w@Wqg etc. ----------------
__global__ __launch_bounds__(256) void k_prep_gemm2(
    const float* __restrict__ fc1w, const float* __restrict__ fc1b,
    const float* __restrict__ wv,
    const unsigned short* __restrict__ tmpWq, const unsigned short* __restrict__ tmpWk,
    unsigned short* __restrict__ qkv2T, float* __restrict__ cvec){
  int c = threadIdx.x, bid = blockIdx.x;
  if (bid < 256){                       // Fq^T[c][d] = sum_e fc1w[d][e]*Wqg[e][c]
    int d = bid; float acc = 0.f;
    for (int e=0;e<256;e++) acc += fc1w[d*256+e]*bf2f(tmpWq[c*256+e]);
    qkv2T[c*256 + d] = f2bf(acc);
  } else if (bid < 512){
    int d = bid-256; float acc = 0.f;
    for (int e=0;e<256;e++) acc += fc1w[d*256+e]*bf2f(tmpWk[c*256+e]);
    qkv2T[(256+c)*256 + d] = f2bf(acc);
  } else if (bid < 768){                // Fv^T[c][d] = sum_e fc1w[d][e]*wv[e][c]
    int d = bid-512; float acc = 0.f;
    for (int e=0;e<256;e++) acc += fc1w[d*256+e]*wv[e*256+c];
    qkv2T[(512+c)*256 + d] = f2bf(acc);
  } else {                              // biases: cq, ck, cv
    float aq=0.f, ak=0.f, av=0.f;
    for (int e=0;e<256;e++){
      float fb = fc1b[e];
      aq += fb*bf2f(tmpWq[c*256+e]);
      ak += fb*bf2f(tmpWk[c*256+e]);
      av += fb*wv[e*256+c];
    }
    cvec[c] = aq; cvec[256+c] = ak; cvec[512+c] = av;
  }
}

// ---------------- kNN: one wave per point, all-static register top16 ----------------
__global__ __launch_bounds__(256) void k_knn(const float* __restrict__ xyz,
                                             int* __restrict__ knn){
  int wave = threadIdx.x >> 6, lane = threadIdx.x & 63;
  int widx = blockIdx.x * 4 + wave;           // 0..16383
  int b = widx >> 12, n = widx & 4095;
  const float* xb = xyz + (size_t)b * NPTS * 3;
  float px = xb[n*3+0], py = xb[n*3+1], pz = xb[n*3+2];
  float x2n = px*px + py*py + pz*pz;
  float dist[16]; int didx[16];
  #pragma unroll
  for (int i=0;i<16;i++){ dist[i] = 3.4e38f; didx[i] = -1; }
  float cmax = 3.4e38f; int cslot = 0;
  for (int t=0;t<64;t++){
    int m = t*64 + lane;                      // lanes own disjoint candidate sets
    float qx = xb[m*3+0], qy = xb[m*3+1], qz = xb[m*3+2];
    float x2m = qx*qx + qy*qy + qz*qz;
    float dot = px*qx + py*qy + pz*qz;
    float d = x2n + x2m - 2.0f*dot;           // same formula as reference
    if (d < cmax){
      #pragma unroll
      for (int i=0;i<16;i++){                 // static predicated insert (no scratch)
        bool hit = (i == cslot);
        dist[i] = hit ? d : dist[i];
        didx[i] = hit ? m : didx[i];
      }
      cmax = dist[0]; cslot = 0;
      #pragma unroll
      for (int i=1;i<16;i++){
        bool g = dist[i] > cmax;
        cmax  = g ? dist[i] : cmax;
        cslot = g ? i : cslot;
      }
    }
  }
  int keep = -1;
  for (int r=0;r<16;r++){
    float lv = dist[0]; int li = didx[0], ls = 0;
    #pragma unroll
    for (int i=1;i<16;i++){
      bool lt = (dist[i] < lv) || (dist[i] == lv && didx[i] < li);
      lv = lt ? dist[i] : lv; li = lt ? didx[i] : li; ls = lt ? i : ls;
    }
    float gv = lv; int gi = li;
    #pragma unroll
    for (int off=32; off>=1; off>>=1){
      float ov = __shfl_xor(gv, off, 64);
      int   oi = __shfl_xor(gi, off, 64);
      if (ov < gv || (ov == gv && oi < gi)){ gv = ov; gi = oi; }
    }
    if (gi == li){
      #pragma unroll
      for (int i=0;i<16;i++) if (i == ls) dist[i] = 3.4e38f;   // static pop
    }
    if (lane == r) keep = gi;
  }
  if (lane < 16) knn[(size_t)widx*16 + lane] = keep;
}

// ---------------- flat GEMM: C(16384 x N) = A(16384x256,bf16) @ BT^T ----------------
// MODE 1: N=1024 -> [qg|kg|v|sc] bf16 with bias cvec
// MODE 2: N=256  -> fout = acc + fc2_b + sc (fp32 final output)
template<int MODE>
__global__ __launch_bounds__(256) void k_gemm(
    const unsigned short* __restrict__ A, const unsigned short* __restrict__ BT,
    const float* __restrict__ bias0,
    unsigned short* __restrict__ out0, unsigned short* __restrict__ out1,
    unsigned short* __restrict__ out2, unsigned short* __restrict__ out3,
    const unsigned short* __restrict__ scbuf, float* __restrict__ fout){
  __shared__ unsigned short As[128*40];
  __shared__ unsigned short Bs[128*40];
  int m0 = blockIdx.x * 128, n0 = blockIdx.y * 128;
  int t = threadIdx.x;
  int lane = t & 63, wave = t >> 6, wm = wave >> 1, wn = wave & 1;
  int lrow = lane & 15, lkg = lane >> 4;
  f32x4 acc[4][4] = {};
  for (int k0 = 0; k0 < 256; k0 += 32){
    int r = t >> 1, h = t & 1;
    const bf16x8* ga = (const bf16x8*)(A  + (size_t)(m0 + r)*256 + k0 + h*16);
    const bf16x8* gb = (const bf16x8*)(BT + (size_t)(n0 + r)*256 + k0 + h*16);
    bf16x8 a0 = ga[0], a1 = ga[1], b0 = gb[0], b1 = gb[1];
    *(bf16x8*)&As[r*40 + h*16]     = a0;
    *(bf16x8*)&As[r*40 + h*16 + 8] = a1;
    *(bf16x8*)&Bs[r*40 + h*16]     = b0;
    *(bf16x8*)&Bs[r*40 + h*16 + 8] = b1;
    __syncthreads();
    bf16x8 af[4], bfr[4];
    #pragma unroll
    for (int fi=0; fi<4; fi++){
      af[fi]  = *(const bf16x8*)&As[(wm*64 + fi*16 + lrow)*40 + lkg*8];
      bfr[fi] = *(const bf16x8*)&Bs[(wn*64 + fi*16 + lrow)*40 + lkg*8];
    }
    #pragma unroll
    for (int fi=0; fi<4; fi++)
      #pragma unroll
      for (int nf=0; nf<4; nf++)
        acc[fi][nf] = MFMA(af[fi], bfr[nf], acc[fi][nf]);
    __syncthreads();
  }
  #pragma unroll
  for (int fi=0; fi<4; fi++)
    #pragma unroll
    for (int nf=0; nf<4; nf++)
      #pragma unroll
      for (int r=0; r<4; r++){
        int row = m0 + wm*64 + fi*16 + lkg*4 + r;
        int col = n0 + wn*64 + nf*16 + lrow;
        float v = acc[fi][nf][r];
        if (MODE == 1){
          float vv = v + bias0[col];
          int sel = col >> 8, cc = col & 255;
          unsigned short* op = (sel==0)?out0:(sel==1)?out1:(sel==2)?out2:out3;
          op[(size_t)row*256 + cc] = f2bf(vv);
        } else {
          fout[(size_t)row*256 + col] = v + bias0[col] + bf2f(scbuf[(size_t)row*256 + col]);
        }
      }
}

// ---------------- stage C: fused per-point transformer core ----------------
// 512 thr = 8 waves in a 2x4 grid: wave (wm,wn4) owns rows wm*32..+32, cols wn4*64..+64.
// 4 points -> M=64 rows. pe kept packed in 16 VGPRs; attn never leaves registers.
// LDS 76KB -> 2 blocks/CU.
__global__ __launch_bounds__(512, 4) void k_stagec(
    const float* __restrict__ xyz, const int* __restrict__ knn,
    const unsigned short* __restrict__ qgbuf, const unsigned short* __restrict__ kgbuf,
    const unsigned short* __restrict__ vbuf,
    const unsigned short* __restrict__ BposT, const unsigned short* __restrict__ g2sT,
    const float* __restrict__ W1, const float* __restrict__ b1d,
    const float* __restrict__ b2d, const float* __restrict__ c1,
    const float* __restrict__ gb2,
    unsigned short* __restrict__ resbuf){
  extern __shared__ char smem[];
  char*           HsB   = smem;                              // 32KB H rows 0-63 (persists)
  char*           A2sB  = smem + 32768;                      // 32KB a1
  unsigned short* qgs   = (unsigned short*)(smem + 65536);   // 2KB (4x256)
  float*          rels  = (float*)(smem + 67584);            // 1KB (dead after phase1)
  float*          W1s   = (float*)(smem + 68608);            // 3KB (dead after phase1)
  unsigned short* resSb = (unsigned short*)(smem + 67584);   // 2KB bf16 (alias)
  float*          b1s   = (float*)(smem + 71680);
  float*          c1s   = (float*)(smem + 72704);
  float*          b2s   = (float*)(smem + 73728);
  float*          gb2s  = (float*)(smem + 74752);
  int*            gidx  = (int*)(smem + 75776);              // 256B

  int t = threadIdx.x;
  int lane = t & 63, w = t >> 6;
  int wm = w >> 2, wn4 = w & 3;           // 2x4 wave grid
  int lrow = lane & 15, lkg = lane >> 4;
  int rowb = wm*32, colg0 = wn4*64;
  int tile = blockIdx.x;                  // 4096 tiles
  int b = tile >> 10;
  int n0 = (tile & 1023) * 4;
  int g0 = b*NPTS + n0;

  // ---- phase 0: stage small data ----
  for (int i = t; i < 768; i += 512) W1s[i] = W1[i];
  if (t < 256){ b1s[t] = b1d[t]; c1s[t] = c1[t]; b2s[t] = b2d[t]; gb2s[t] = gb2[t]*0.0625f; }
  if (t < 64){
    int p = t >> 4, kk = t & 15;
    int id = knn[(size_t)(g0 + p)*16 + kk];
    gidx[t] = b*NPTS + id;
    const float* cp  = xyz + (size_t)(b*NPTS + n0 + p)*3;
    const float* np_ = xyz + (size_t)(b*NPTS + id)*3;
    rels[t*4+0] = cp[0]-np_[0]; rels[t*4+1] = cp[1]-np_[1]; rels[t*4+2] = cp[2]-np_[2];
  }
  if (t < 256){ int e = t * 4; int p = e >> 8, c = e & 255;
    *(s16x4*)&qgs[e] = *(const s16x4*)&qgbuf[(size_t)(g0 + p)*256 + c]; }
  __syncthreads();

  // ---- phase 1: H = relu(rel @ W1 + b1)  (64 rows x 256 cols) ----
  {
    int r = t >> 3, c0 = (t & 7) * 32;
    float rx = rels[r*4], ry = rels[r*4+1], rz = rels[r*4+2];
    #pragma unroll
    for (int cc = 0; cc < 32; cc += 8){
      int c = c0 + cc;
      bf16x8 hv;
      #pragma unroll
      for (int j=0;j<8;j++){
        float h = rx*W1s[c+j] + ry*W1s[256+c+j] + rz*W1s[512+c+j] + b1s[c+j];
        hv[j] = (short)f2bf(fmaxf(h, 0.0f));
      }
      *(bf16x8*)(HsB + swz(r, c*2)) = hv;
    }
  }
  __syncthreads();                        // B1: H visible

  // ---- phase 2: pe = H @ W2 + b2 -> packed bf16 pairs (16 VGPRs) ----
  unsigned int peP[16];
  {
    const unsigned short* BT = BposT + (size_t)256*256;
    f32x4 acce[2][4] = {};
    for (int k0 = 0; k0 < 256; k0 += 32){
      bf16x8 af[2];
      #pragma unroll
      for (int fi=0; fi<2; fi++)
        af[fi] = *(const bf16x8*)(HsB + swz(rowb + fi*16 + lrow, k0*2 + lkg*16));
      bf16x8 bfr[4];
      #pragma unroll
      for (int nf=0; nf<4; nf++)
        bfr[nf] = *(const bf16x8*)(BT + (size_t)(colg0 + nf*16 + lrow)*256 + k0 + lkg*8);
      #pragma unroll
      for (int fi=0; fi<2; fi++)
        #pragma unroll
        for (int nf=0; nf<4; nf++)
          acce[fi][nf] = MFMA(af[fi], bfr[nf], acce[fi][nf]);
    }
    #pragma unroll
    for (int fi=0; fi<2; fi++)
      #pragma unroll
      for (int nf=0; nf<4; nf++){
        int col = colg0 + nf*16 + lrow;
        #pragma unroll
        for (int rp=0; rp<2; rp++){
          unsigned int lo = f2bf(acce[fi][nf][2*rp]   + b2s[col]);
          unsigned int hi = f2bf(acce[fi][nf][2*rp+1] + b2s[col]);
          peP[fi*8 + nf*2 + rp] = lo | (hi << 16);
        }
      }
  }

  // ---- phase 3: posg = H @ W2g1 ; a1 = relu(posg + qg - kg + c1) -> A2 ----
  {
    f32x4 accg[2][4] = {};
    for (int k0 = 0; k0 < 256; k0 += 32){
      bf16x8 af[2];
      #pragma unroll
      for (int fi=0; fi<2; fi++)
        af[fi] = *(const bf16x8*)(HsB + swz(rowb + fi*16 + lrow, k0*2 + lkg*16));
      bf16x8 bfr[4];
      #pragma unroll
      for (int nf=0; nf<4; nf++)
        bfr[nf] = *(const bf16x8*)(BposT + (size_t)(colg0 + nf*16 + lrow)*256 + k0 + lkg*8);
      #pragma unroll
      for (int fi=0; fi<2; fi++)
        #pragma unroll
        for (int nf=0; nf<4; nf++)
          accg[fi][nf] = MFMA(af[fi], bfr[nf], accg[fi][nf]);
    }
    #pragma unroll
    for (int fi=0; fi<2; fi++)
      #pragma unroll
      for (int nf=0; nf<4; nf++)
        #pragma unroll
        for (int r=0; r<4; r++){
          int row = rowb + fi*16 + lkg*4 + r;
          int col = colg0 + nf*16 + lrow;
          float a1 = accg[fi][nf][r] + bf2f(qgs[(wm*2+fi)*256 + col])
                   - bf2f(kgbuf[(size_t)gidx[row]*256 + col]) + c1s[col];
          *(unsigned short*)(A2sB + swz(row, col*2)) = f2bf(fmaxf(a1, 0.0f));
        }
  }
  __syncthreads();                        // B2: A2 visible

  // ---- phase 4: s = A2 @ (g2/16); softmax over K=16; res = sum attn*(v+pe) ----
  {
    f32x4 acc2[2][4] = {};
    for (int k0 = 0; k0 < 256; k0 += 32){
      bf16x8 af[2];
      #pragma unroll
      for (int fi=0; fi<2; fi++)
        af[fi] = *(const bf16x8*)(A2sB + swz(rowb + fi*16 + lrow, k0*2 + lkg*16));
      bf16x8 bfr[4];
      #pragma unroll
      for (int nf=0; nf<4; nf++)
        bfr[nf] = *(const bf16x8*)(g2sT + (size_t)(colg0 + nf*16 + lrow)*256 + k0 + lkg*8);
      #pragma unroll
      for (int fi=0; fi<2; fi++)
        #pragma unroll
        for (int nf=0; nf<4; nf++)
          acc2[fi][nf] = MFMA(af[fi], bfr[nf], acc2[fi][nf]);
    }
    #pragma unroll
    for (int fi=0; fi<2; fi++)
      #pragma unroll
      for (int nf=0; nf<4; nf++){
        int col = colg0 + nf*16 + lrow;
        float s[4], e[4];
        #pragma unroll
        for (int r=0;r<4;r++) s[r] = acc2[fi][nf][r] + gb2s[col];
        float mx = fmaxf(fmaxf(s[0],s[1]), fmaxf(s[2],s[3]));
        mx = fmaxf(mx, __shfl_xor(mx, 16, 64));
        mx = fmaxf(mx, __shfl_xor(mx, 32, 64));
        float sm = 0.f;
        #pragma unroll
        for (int r=0;r<4;r++){ e[r] = __expf(s[r]-mx); sm += e[r]; }
        sm += __shfl_xor(sm, 16, 64);
        sm += __shfl_xor(sm, 32, 64);
        float rs = 1.0f / sm;
        float tsum = 0.f;
        #pragma unroll
        for (int r=0;r<4;r++){
          int row = rowb + fi*16 + lkg*4 + r;
          unsigned int pw = peP[fi*8 + nf*2 + (r>>1)];
          float pe = bf2f((unsigned short)((r&1) ? (pw>>16) : (pw & 0xffff)));
          float vv = bf2f(vbuf[(size_t)gidx[row]*256 + col]) + pe;
          tsum += (e[r]*rs) * vv;
        }
        tsum += __shfl_xor(tsum, 16, 64);
        tsum += __shfl_xor(tsum, 32, 64);
        if (lkg == 0) resSb[(wm*2+fi)*256 + col] = f2bf(tsum);
      }
  }
  __syncthreads();                        // B3: resSb visible

  // ---- phase 5: store res (bf16, vectorized) ----
  if (t < 256){ int e = t * 4; int p = e >> 8, c = e & 255;
    *(s16x4*)&resbuf[(size_t)(g0 + p)*256 + c] = *(s16x4*)&resSb[e]; }
}

// ---------------- host ----------------
extern "C" void kernel_launch(void* const* d_in, const int* in_sizes, int n_in,
                              void* d_out, int out_size, void* d_ws, size_t ws_size,
                              hipStream_t stream){
  (void)in_sizes; (void)n_in; (void)out_size; (void)ws_size;
  const float* xyz  = (const float*)d_in[0];
  const float* feat = (const float*)d_in[1];
  const float* W1   = (const float*)d_in[2];
  const float* b1d  = (const float*)d_in[3];
  const float* W2   = (const float*)d_in[4];
  const float* b2d  = (const float*)d_in[5];
  const float* fc1w = (const float*)d_in[6];
  const float* fc1b = (const float*)d_in[7];
  const float* wq   = (const float*)d_in[8];
  const float* wk   = (const float*)d_in[9];
  const float* wv   = (const float*)d_in[10];
  const float* g1   = (const float*)d_in[11];
  const float* gb1  = (const float*)d_in[12];
  const float* g2   = (const float*)d_in[13];
  const float* gb2  = (const float*)d_in[14];
  const float* fc2w = (const float*)d_in[15];
  const float* fc2b = (const float*)d_in[16];
  const float* scw  = (const float*)d_in[17];
  const float* scb  = (const float*)d_in[18];

  char* ws = (char*)d_ws;
  size_t off = 0;
  auto alloc = [&](size_t bytes)->void*{ void* p = ws + off; off += (bytes + 255) & ~(size_t)255; return p; };
  int*            knn    = (int*)alloc((size_t)NTOT*16*4);
  unsigned short* Xb     = (unsigned short*)alloc((size_t)NTOT*256*2); // reused as res
  unsigned short* qg     = (unsigned short*)alloc((size_t)NTOT*256*2);
  unsigned short* kg     = (unsigned short*)alloc((size_t)NTOT*256*2);
  unsigned short* vbuf   = (unsigned short*)alloc((size_t)NTOT*256*2);
  unsigned short* scbuf  = (unsigned short*)alloc((size_t)NTOT*256*2);
  unsigned short* qkv2T  = (unsigned short*)alloc(1024*256*2);
  unsigned short* tmpWq  = (unsigned short*)alloc(256*256*2);
  unsigned short* tmpWk  = (unsigned short*)alloc(256*256*2);
  unsigned short* BposT  = (unsigned short*)alloc(512*256*2);
  unsigned short* g2sT   = (unsigned short*)alloc(256*256*2);
  unsigned short* fc2T   = (unsigned short*)alloc(256*256*2);
  float*          c1     = (float*)alloc(256*4);
  float*          cvec   = (float*)alloc(1024*4);
  unsigned short* res    = Xb;   // alias: Xb dead after gemm<1>

  k_convert<<<4096, 256, 0, stream>>>(feat, Xb, NTOT*256);
  k_prep_mats<<<256, 256, 0, stream>>>(scw, g2, fc2w, W2, scb, qkv2T, g2sT, fc2T, BposT, cvec);
  k_prep_gemm<<<769, 256, 0, stream>>>(wq, wk, g1, W2, b2d, gb1, tmpWq, tmpWk, BposT, c1);
  k_prep_gemm2<<<769, 256, 0, stream>>>(fc1w, fc1b, wv, tmpWq, tmpWk, qkv2T, cvec);
  k_knn<<<4096, 256, 0, stream>>>(xyz, knn);
  k_gemm<1><<<dim3(128,8), 256, 0, stream>>>(Xb, qkv2T, cvec, qg, kg, vbuf, scbuf, nullptr, nullptr);
  hipFuncSetAttribute((const void*)k_stagec, hipFuncAttributeMaxDynamicSharedMemorySize, 76032);
  k_stagec<<<4096, 512, 76032, stream>>>(xyz, knn, qg, kg, vbuf, BposT, g2sT, W1, b1d, b2d, c1, gb2, res);
  k_gemm<2><<<dim3(128,2), 256, 0, stream>>>(res, fc2T, fc2b, nullptr, nullptr, nullptr, nullptr, scbuf, (float*)d_out);
}

// Round 5
// 665.771 us; speedup vs baseline: 1.2115x; 1.2115x over previous
//
#include <hip/hip_runtime.h>
#include <math.h>

typedef __attribute__((ext_vector_type(8))) short bf16x8;
typedef __attribute__((ext_vector_type(4))) float f32x4;
typedef __attribute__((ext_vector_type(4))) short s16x4;
typedef unsigned int u32;

#define NBATCH 4
#define NPTS   4096
#define NTOT   (NBATCH*NPTS)     // 16384 points
#define NROWS  (NTOT*16)         // 262144 (point,neighbor) rows

__device__ __forceinline__ float bf2f(unsigned short h){
  unsigned int u = ((unsigned int)h) << 16;
  return __builtin_bit_cast(float, u);
}
__device__ __forceinline__ unsigned short f2bf(float f){
  unsigned int u = __builtin_bit_cast(unsigned int, f);
  u += 0x7FFFu + ((u >> 16) & 1u);   // RNE
  return (unsigned short)(u >> 16);
}

#define MFMA(a,b,c) __builtin_amdgcn_mfma_f32_16x16x32_bf16((a),(b),(c),0,0,0)

typedef u32 __attribute__((address_space(1))) gas_u32;
typedef u32 __attribute__((address_space(3))) las_u32;
__device__ __forceinline__ void gl_lds16(const void* g, void* l){
  __builtin_amdgcn_global_load_lds((const gas_u32*)g, (las_u32*)l, 16, 0, 0);
}

// ---------------- prep: features -> bf16 ----------------
__global__ __launch_bounds__(256) void k_convert(const float* __restrict__ x,
                                                 unsigned short* __restrict__ xb, int n){
  int i = (blockIdx.x * 256 + threadIdx.x) * 4;
  if (i < n){
    float4 v = *(const float4*)(x + i);
    s16x4 o;
    o[0] = (short)f2bf(v.x); o[1] = (short)f2bf(v.y);
    o[2] = (short)f2bf(v.z); o[3] = (short)f2bf(v.w);
    *(s16x4*)(xb + i) = o;
  }
}

// ---------------- prep: transposed bf16 weight copies ----------------
__global__ __launch_bounds__(256) void k_prep_mats(
    const float* __restrict__ scw, const float* __restrict__ g2,
    const float* __restrict__ fc2, const float* __restrict__ W2,
    const float* __restrict__ scb,
    unsigned short* __restrict__ qkv2T, unsigned short* __restrict__ g2sT,
    unsigned short* __restrict__ fc2T, unsigned short* __restrict__ BposT,
    float* __restrict__ cvec){
  int c = blockIdx.x, d = threadIdx.x;
  qkv2T[(768+c)*256 + d] = f2bf(scw[d*256 + c]);             // sc^T
  g2sT[c*256 + d]        = f2bf(g2[d*256 + c] * 0.0625f);    // fold 1/sqrt(DM)=1/16
  fc2T[c*256 + d]        = f2bf(fc2[d*256 + c]);
  BposT[(256+c)*256 + d] = f2bf(W2[d*256 + c]);              // W2^T (pe)
  if (d == 0) cvec[768 + c] = scb[c];
}

// ---------------- prep stage 1: Wqg = wq@g1, Wkg = wk@g1, W2g1, c1 ----------------
__global__ __launch_bounds__(256) void k_prep_gemm(
    const float* __restrict__ wq, const float* __restrict__ wk,
    const float* __restrict__ g1, const float* __restrict__ W2,
    const float* __restrict__ b2d, const float* __restrict__ gb1,
    unsigned short* __restrict__ tmpWq, unsigned short* __restrict__ tmpWk,
    unsigned short* __restrict__ BposT, float* __restrict__ c1){
  int c = threadIdx.x, bid = blockIdx.x;
  if (bid < 256){
    int d = bid; float acc = 0.f;
    for (int e=0;e<256;e++) acc += wq[d*256+e]*g1[e*256+c];
    tmpWq[c*256 + d] = f2bf(acc);
  } else if (bid < 512){
    int d = bid-256; float acc = 0.f;
    for (int e=0;e<256;e++) acc += wk[d*256+e]*g1[e*256+c];
    tmpWk[c*256 + d] = f2bf(acc);
  } else if (bid < 768){
    int d = bid-512; float acc = 0.f;
    for (int e=0;e<256;e++) acc += W2[d*256+e]*g1[e*256+c];
    BposT[c*256 + d] = f2bf(acc);
  } else {
    float acc = 0.f;
    for (int e=0;e<256;e++) acc += b2d[e]*g1[e*256+c];
    c1[c] = acc + gb1[c];
  }
}

// ---------------- prep stage 2: fold fc1 into QKV ----------------
__global__ __launch_bounds__(256) void k_prep_gemm2(
    const float* __restrict__ fc1w, const float* __restrict__ fc1b,
    const float* __restrict__ wv,
    const unsigned short* __restrict__ tmpWq, const unsigned short* __restrict__ tmpWk,
    unsigned short* __restrict__ qkv2T, float* __restrict__ cvec){
  int c = threadIdx.x, bid = blockIdx.x;
  if (bid < 256){
    int d = bid; float acc = 0.f;
    for (int e=0;e<256;e++) acc += fc1w[d*256+e]*bf2f(tmpWq[c*256+e]);
    qkv2T[c*256 + d] = f2bf(acc);
  } else if (bid < 512){
    int d = bid-256; float acc = 0.f;
    for (int e=0;e<256;e++) acc += fc1w[d*256+e]*bf2f(tmpWk[c*256+e]);
    qkv2T[(256+c)*256 + d] = f2bf(acc);
  } else if (bid < 768){
    int d = bid-512; float acc = 0.f;
    for (int e=0;e<256;e++) acc += fc1w[d*256+e]*wv[e*256+c];
    qkv2T[(512+c)*256 + d] = f2bf(acc);
  } else {
    float aq=0.f, ak=0.f, av=0.f;
    for (int e=0;e<256;e++){
      float fb = fc1b[e];
      aq += fb*bf2f(tmpWq[c*256+e]);
      ak += fb*bf2f(tmpWk[c*256+e]);
      av += fb*wv[e*256+c];
    }
    cvec[c] = aq; cvec[256+c] = ak; cvec[512+c] = av;
  }
}

// ---------------- kNN: one wave per point -> gidx + rel (no idx buffer) ----------------
__global__ __launch_bounds__(256) void k_knn(const float* __restrict__ xyz,
                                             int* __restrict__ gidxbuf,
                                             float4* __restrict__ relbuf){
  int wave = threadIdx.x >> 6, lane = threadIdx.x & 63;
  int widx = blockIdx.x * 4 + wave;
  int b = widx >> 12, n = widx & 4095;
  const float* xb = xyz + (size_t)b * NPTS * 3;
  float px = xb[n*3+0], py = xb[n*3+1], pz = xb[n*3+2];
  float x2n = px*px + py*py + pz*pz;
  float dist[16]; int didx[16];
  #pragma unroll
  for (int i=0;i<16;i++){ dist[i] = 3.4e38f; didx[i] = -1; }
  float cmax = 3.4e38f; int cslot = 0;
  for (int t=0;t<64;t++){
    int m = t*64 + lane;
    float qx = xb[m*3+0], qy = xb[m*3+1], qz = xb[m*3+2];
    float x2m = qx*qx + qy*qy + qz*qz;
    float dot = px*qx + py*qy + pz*qz;
    float d = x2n + x2m - 2.0f*dot;
    if (d < cmax){
      #pragma unroll
      for (int i=0;i<16;i++){
        bool hit = (i == cslot);
        dist[i] = hit ? d : dist[i];
        didx[i] = hit ? m : didx[i];
      }
      cmax = dist[0]; cslot = 0;
      #pragma unroll
      for (int i=1;i<16;i++){
        bool g = dist[i] > cmax;
        cmax  = g ? dist[i] : cmax;
        cslot = g ? i : cslot;
      }
    }
  }
  int keep = -1;
  for (int r=0;r<16;r++){
    float lv = dist[0]; int li = didx[0], ls = 0;
    #pragma unroll
    for (int i=1;i<16;i++){
      bool lt = (dist[i] < lv) || (dist[i] == lv && didx[i] < li);
      lv = lt ? dist[i] : lv; li = lt ? didx[i] : li; ls = lt ? i : ls;
    }
    float gv = lv; int gi = li;
    #pragma unroll
    for (int off=32; off>=1; off>>=1){
      float ov = __shfl_xor(gv, off, 64);
      int   oi = __shfl_xor(gi, off, 64);
      if (ov < gv || (ov == gv && oi < gi)){ gv = ov; gi = oi; }
    }
    if (gi == li){
      #pragma unroll
      for (int i=0;i<16;i++) if (i == ls) dist[i] = 3.4e38f;
    }
    if (lane == r) keep = gi;
  }
  if (lane < 16){
    size_t R = (size_t)widx*16 + lane;
    gidxbuf[R] = b*NPTS + keep;
    const float* np_ = xb + keep*3;
    relbuf[R] = make_float4(px - np_[0], py - np_[1], pz - np_[2], 0.f);
  }
}

// ================= unified m97-style GEMM: 128x128 tile, BK=32, global_load_lds =======
// MODE 0: QKV  A=Xb(16384x256)  BT=qkv2T N=1024 -> qg|kg|v|sc (+cvec)
// MODE 2: G2   A=on-the-fly H   BT=BposT N=512  -> a1 (relu(posg+qg-kg+c1)), vpe (pe+b2+v)
// MODE 3: G3   A=a1             BT=g2sT  N=256  -> softmax+combine(vpe) -> res
// MODE 4: FIN  A=res            BT=fc2T  N=256  -> fp32 out (+fc2b+sc)
template<int MODE>
__global__ __launch_bounds__(256) void k_mm(
    const unsigned short* __restrict__ A, const unsigned short* __restrict__ BT,
    int rowbase,
    const float* __restrict__ bias, const float* __restrict__ b2v,
    const unsigned short* __restrict__ qg, const unsigned short* __restrict__ kg,
    const unsigned short* __restrict__ vb,
    const float4* __restrict__ relbuf, const int* __restrict__ gidxbuf,
    const float* __restrict__ W1, const float* __restrict__ b1d,
    unsigned short* __restrict__ o0, unsigned short* __restrict__ o1,
    unsigned short* __restrict__ o2, unsigned short* __restrict__ o3,
    const unsigned short* __restrict__ vper,
    float* __restrict__ fout){
  __shared__ unsigned short As[4096];   // 128 x 32 linear
  __shared__ unsigned short Bs[4096];
  __shared__ float  W1s[768];
  __shared__ float  b1s[256];
  __shared__ float4 relS[128];
  __shared__ int    gidxS[128];

  int t = threadIdx.x;
  int lane = t & 63, w = t >> 6, wm = w >> 1, wn = w & 1;
  int lrow = lane & 15, lkg = lane >> 4;
  int m0 = blockIdx.x * 128, n0 = blockIdx.y * 128;

  if constexpr (MODE == 2){
    if (t < 128){
      relS[t]  = relbuf[(size_t)rowbase + m0 + t];
      gidxS[t] = gidxbuf[(size_t)rowbase + m0 + t];
    }
    for (int i = t; i < 768; i += 256) W1s[i] = W1[i];
    b1s[t] = b1d[t];
    __syncthreads();
  }

  int sr = t >> 2, sc = (t & 3) * 8;               // staging: row, col(8 bf16=16B)
  unsigned short* lA = As + (w << 9);              // wave-uniform LDS base (1KB/wave)
  unsigned short* lB = Bs + (w << 9);
  const unsigned short* gB = BT + (size_t)(n0 + sr)*256 + sc;

  f32x4 acc[4][4] = {};
  for (int k0 = 0; k0 < 256; k0 += 32){
    if constexpr (MODE == 2){
      // compute H tile rows [m0,m0+128) cols [k0,k0+32) in-place
      int r = t >> 1, h = (t & 1) << 4;
      float4 rl = relS[r];
      bf16x8 h0, h1;
      #pragma unroll
      for (int j = 0; j < 8; j++){
        int c = k0 + h + j;
        float x0 = rl.x*W1s[c]   + rl.y*W1s[256+c]   + rl.z*W1s[512+c]   + b1s[c];
        float x1 = rl.x*W1s[c+8] + rl.y*W1s[256+c+8] + rl.z*W1s[512+c+8] + b1s[c+8];
        h0[j] = (short)f2bf(fmaxf(x0, 0.f));
        h1[j] = (short)f2bf(fmaxf(x1, 0.f));
      }
      *(bf16x8*)&As[r*32 + h]     = h0;
      *(bf16x8*)&As[r*32 + h + 8] = h1;
    } else {
      const unsigned short* gA = A + (size_t)(m0 + sr)*256 + k0 + sc;
      gl_lds16(gA,          lA);
      gl_lds16(gA + 64*256, lA + 2048);
    }
    gl_lds16(gB + k0,          lB);
    gl_lds16(gB + k0 + 64*256, lB + 2048);
    __syncthreads();
    bf16x8 af[4], bfr[4];
    #pragma unroll
    for (int fi = 0; fi < 4; fi++)
      af[fi] = *(const bf16x8*)&As[(wm*64 + fi*16 + lrow)*32 + lkg*8];
    #pragma unroll
    for (int nf = 0; nf < 4; nf++)
      bfr[nf] = *(const bf16x8*)&Bs[(wn*64 + nf*16 + lrow)*32 + lkg*8];
    #pragma unroll
    for (int fi = 0; fi < 4; fi++)
      #pragma unroll
      for (int nf = 0; nf < 4; nf++)
        acc[fi][nf] = MFMA(af[fi], bfr[nf], acc[fi][nf]);
    __syncthreads();
  }

  if constexpr (MODE == 0){
    #pragma unroll
    for (int fi=0; fi<4; fi++)
      #pragma unroll
      for (int nf=0; nf<4; nf++)
        #pragma unroll
        for (int r=0;r<4;r++){
          int row = m0 + wm*64 + fi*16 + lkg*4 + r;
          int col = n0 + wn*64 + nf*16 + lrow;
          float v = acc[fi][nf][r] + bias[col];
          int sel = col >> 8, cc = col & 255;
          unsigned short* op = (sel==0)?o0:(sel==1)?o1:(sel==2)?o2:o3;
          op[(size_t)row*256 + cc] = f2bf(v);
        }
  } else if constexpr (MODE == 2){
    #pragma unroll
    for (int fi=0; fi<4; fi++){
      int g = (rowbase + m0 + wm*64 + fi*16) >> 4;     // point id (16 rows = 1 point)
      #pragma unroll
      for (int nf=0; nf<4; nf++){
        int colg = n0 + wn*64 + nf*16 + lrow;          // 0..511
        if (colg < 256){
          float qv = bf2f(qg[(size_t)g*256 + colg]) + bias[colg];   // bias = c1
          #pragma unroll
          for (int r=0;r<4;r++){
            int rl_ = wm*64 + fi*16 + lkg*4 + r;
            int gi = gidxS[rl_];
            float a1 = acc[fi][nf][r] + qv - bf2f(kg[(size_t)gi*256 + colg]);
            o0[(size_t)(m0 + rl_)*256 + colg] = f2bf(fmaxf(a1, 0.f));
          }
        } else {
          int c2 = colg - 256;
          float bb = b2v[c2];
          #pragma unroll
          for (int r=0;r<4;r++){
            int rl_ = wm*64 + fi*16 + lkg*4 + r;
            int gi = gidxS[rl_];
            float vpe = acc[fi][nf][r] + bb + bf2f(vb[(size_t)gi*256 + c2]);
            o1[(size_t)(m0 + rl_)*256 + c2] = f2bf(vpe);
          }
        }
      }
    }
  } else if constexpr (MODE == 3){
    #pragma unroll
    for (int fi=0; fi<4; fi++){
      int g = (rowbase + m0 + wm*64 + fi*16) >> 4;
      #pragma unroll
      for (int nf=0; nf<4; nf++){
        int colg = n0 + wn*64 + nf*16 + lrow;          // 0..255
        float s[4], e[4];
        #pragma unroll
        for (int r=0;r<4;r++) s[r] = acc[fi][nf][r] + bias[colg]*0.0625f;  // bias = gb2
        float mx = fmaxf(fmaxf(s[0],s[1]), fmaxf(s[2],s[3]));
        mx = fmaxf(mx, __shfl_xor(mx,16,64));
        mx = fmaxf(mx, __shfl_xor(mx,32,64));
        float sm = 0.f;
        #pragma unroll
        for (int r=0;r<4;r++){ e[r] = __expf(s[r]-mx); sm += e[r]; }
        sm += __shfl_xor(sm,16,64);
        sm += __shfl_xor(sm,32,64);
        float rs = 1.f/sm, tsum = 0.f;
        #pragma unroll
        for (int r=0;r<4;r++){
          int rl_ = wm*64 + fi*16 + lkg*4 + r;
          tsum += (e[r]*rs) * bf2f(vper[(size_t)(m0 + rl_)*256 + colg]);
        }
        tsum += __shfl_xor(tsum,16,64);
        tsum += __shfl_xor(tsum,32,64);
        if (lkg == 0) o0[(size_t)g*256 + colg] = f2bf(tsum);
      }
    }
  } else {   // FIN
    #pragma unroll
    for (int fi=0; fi<4; fi++)
      #pragma unroll
      for (int nf=0; nf<4; nf++)
        #pragma unroll
        for (int r=0;r<4;r++){
          int row = m0 + wm*64 + fi*16 + lkg*4 + r;
          int col = n0 + wn*64 + nf*16 + lrow;
          fout[(size_t)row*256 + col] = acc[fi][nf][r] + bias[col]
                                      + bf2f(qg[(size_t)row*256 + col]);  // qg slot = scbuf
        }
  }
}

// ---------------- host ----------------
extern "C" void kernel_launch(void* const* d_in, const int* in_sizes, int n_in,
                              void* d_out, int out_size, void* d_ws, size_t ws_size,
                              hipStream_t stream){
  (void)in_sizes; (void)n_in; (void)out_size;
  const float* xyz  = (const float*)d_in[0];
  const float* feat = (const float*)d_in[1];
  const float* W1   = (const float*)d_in[2];
  const float* b1d  = (const float*)d_in[3];
  const float* W2   = (const float*)d_in[4];
  const float* b2d  = (const float*)d_in[5];
  const float* fc1w = (const float*)d_in[6];
  const float* fc1b = (const float*)d_in[7];
  const float* wq   = (const float*)d_in[8];
  const float* wk   = (const float*)d_in[9];
  const float* wv   = (const float*)d_in[10];
  const float* g1   = (const float*)d_in[11];
  const float* gb1  = (const float*)d_in[12];
  const float* g2   = (const float*)d_in[13];
  const float* gb2  = (const float*)d_in[14];
  const float* fc2w = (const float*)d_in[15];
  const float* fc2b = (const float*)d_in[16];
  const float* scw  = (const float*)d_in[17];
  const float* scb  = (const float*)d_in[18];

  char* ws = (char*)d_ws;
  size_t off = 0;
  auto alloc = [&](size_t bytes)->void*{ void* p = ws + off; off += (bytes + 255) & ~(size_t)255; return p; };
  unsigned short* Xb     = (unsigned short*)alloc((size_t)NTOT*256*2);  // reused as res
  unsigned short* qgb    = (unsigned short*)alloc((size_t)NTOT*256*2);
  unsigned short* kgb    = (unsigned short*)alloc((size_t)NTOT*256*2);
  unsigned short* vbb    = (unsigned short*)alloc((size_t)NTOT*256*2);
  unsigned short* scbuf  = (unsigned short*)alloc((size_t)NTOT*256*2);
  int*            gidxbuf= (int*)alloc((size_t)NROWS*4);
  float4*         relbuf = (float4*)alloc((size_t)NROWS*16);
  unsigned short* qkv2T  = (unsigned short*)alloc(1024*256*2);
  unsigned short* tmpWq  = (unsigned short*)alloc(256*256*2);
  unsigned short* tmpWk  = (unsigned short*)alloc(256*256*2);
  unsigned short* BposT  = (unsigned short*)alloc(512*256*2);
  unsigned short* g2sT   = (unsigned short*)alloc(256*256*2);
  unsigned short* fc2T   = (unsigned short*)alloc(256*256*2);
  float*          c1     = (float*)alloc(256*4);
  float*          cvec   = (float*)alloc(1024*4);
  unsigned short* res    = Xb;

  // adaptive chunk: a1 + vpe cost CR*1024 bytes
  int CR = NROWS;
  while (CR > 16384 && off + (size_t)CR*1024 > ws_size) CR >>= 1;
  unsigned short* a1buf  = (unsigned short*)alloc((size_t)CR*256*2);
  unsigned short* vpebuf = (unsigned short*)alloc((size_t)CR*256*2);

  k_convert<<<4096, 256, 0, stream>>>(feat, Xb, NTOT*256);
  k_prep_mats<<<256, 256, 0, stream>>>(scw, g2, fc2w, W2, scb, qkv2T, g2sT, fc2T, BposT, cvec);
  k_prep_gemm<<<769, 256, 0, stream>>>(wq, wk, g1, W2, b2d, gb1, tmpWq, tmpWk, BposT, c1);
  k_prep_gemm2<<<769, 256, 0, stream>>>(fc1w, fc1b, wv, tmpWq, tmpWk, qkv2T, cvec);
  k_knn<<<4096, 256, 0, stream>>>(xyz, gidxbuf, relbuf);

  k_mm<0><<<dim3(128, 8), 256, 0, stream>>>(Xb, qkv2T, 0, cvec, nullptr,
      nullptr, nullptr, nullptr, nullptr, nullptr, nullptr, nullptr,
      qgb, kgb, vbb, scbuf, nullptr, nullptr);

  for (int c0 = 0; c0 < NROWS; c0 += CR){
    k_mm<2><<<dim3(CR/128, 4), 256, 0, stream>>>(nullptr, BposT, c0, c1, b2d,
        qgb, kgb, vbb, relbuf, gidxbuf, W1, b1d,
        a1buf, vpebuf, nullptr, nullptr, nullptr, nullptr);
    k_mm<3><<<dim3(CR/128, 2), 256, 0, stream>>>(a1buf, g2sT, c0, gb2, nullptr,
        nullptr, nullptr, nullptr, nullptr, nullptr, nullptr, nullptr,
        res, nullptr, nullptr, nullptr, vpebuf, nullptr);
  }

  k_mm<4><<<dim3(128, 2), 256, 0, stream>>>(res, fc2T, 0, fc2b, nullptr,
      scbuf, nullptr, nullptr, nullptr, nullptr, nullptr, nullptr,
      nullptr, nullptr, nullptr, nullptr, nullptr, (float*)d_out);
}

// Round 6
// 602.877 us; speedup vs baseline: 1.3379x; 1.1043x over previous
//
#include <hip/hip_runtime.h>
#include <math.h>

typedef __attribute__((ext_vector_type(8))) short bf16x8;
typedef __attribute__((ext_vector_type(4))) float f32x4;
typedef __attribute__((ext_vector_type(4))) short s16x4;
typedef unsigned int u32;
typedef unsigned long long u64;

#define NBATCH 4
#define NPTS   4096
#define NTOT   (NBATCH*NPTS)     // 16384 points
#define NROWS  (NTOT*16)         // 262144 (point,neighbor) rows

__device__ __forceinline__ float bf2f(unsigned short h){
  unsigned int u = ((unsigned int)h) << 16;
  return __builtin_bit_cast(float, u);
}
__device__ __forceinline__ unsigned short f2bf(float f){
  unsigned int u = __builtin_bit_cast(unsigned int, f);
  u += 0x7FFFu + ((u >> 16) & 1u);   // RNE
  return (unsigned short)(u >> 16);
}

#define MFMA(a,b,c) __builtin_amdgcn_mfma_f32_16x16x32_bf16((a),(b),(c),0,0,0)

typedef u32 __attribute__((address_space(1))) gas_u32;
typedef u32 __attribute__((address_space(3))) las_u32;
__device__ __forceinline__ void gl_lds16(const void* g, void* l){
  __builtin_amdgcn_global_load_lds((const gas_u32*)g, (las_u32*)l, 16, 0, 0);
}

// wave-internal LDS ordering fence (rule #18 pattern)
__device__ __forceinline__ void wfence(){
  asm volatile("s_waitcnt lgkmcnt(0)" ::: "memory");
  __builtin_amdgcn_sched_barrier(0);
}

// ---------------- prep: features -> bf16 ----------------
__global__ __launch_bounds__(256) void k_convert(const float* __restrict__ x,
                                                 unsigned short* __restrict__ xb, int n){
  int i = (blockIdx.x * 256 + threadIdx.x) * 4;
  if (i < n){
    float4 v = *(const float4*)(x + i);
    s16x4 o;
    o[0] = (short)f2bf(v.x); o[1] = (short)f2bf(v.y);
    o[2] = (short)f2bf(v.z); o[3] = (short)f2bf(v.w);
    *(s16x4*)(xb + i) = o;
  }
}

// ---------------- prep: xyz -> float4 (x,y,z,|p|^2) ----------------
__global__ __launch_bounds__(256) void k_xyzw(const float* __restrict__ xyz,
                                              float4* __restrict__ xyzw){
  int i = blockIdx.x * 256 + threadIdx.x;   // 16384
  float x = xyz[i*3], y = xyz[i*3+1], z = xyz[i*3+2];
  xyzw[i] = make_float4(x, y, z, x*x + y*y + z*z);
}

// ---------------- prep: transposed bf16 weight copies ----------------
__global__ __launch_bounds__(256) void k_prep_mats(
    const float* __restrict__ scw, const float* __restrict__ g2,
    const float* __restrict__ fc2, const float* __restrict__ W2,
    const float* __restrict__ scb,
    unsigned short* __restrict__ qkv2T, unsigned short* __restrict__ g2sT,
    unsigned short* __restrict__ fc2T, unsigned short* __restrict__ BposT,
    float* __restrict__ cvec){
  int c = blockIdx.x, d = threadIdx.x;
  qkv2T[(768+c)*256 + d] = f2bf(scw[d*256 + c]);             // sc^T
  g2sT[c*256 + d]        = f2bf(g2[d*256 + c] * 0.0625f);    // fold 1/sqrt(DM)=1/16
  fc2T[c*256 + d]        = f2bf(fc2[d*256 + c]);
  BposT[(256+c)*256 + d] = f2bf(W2[d*256 + c]);              // W2^T (pe)
  if (d == 0) cvec[768 + c] = scb[c];
}

// ---------------- prep stage 1: Wqg = wq@g1, Wkg = wk@g1, W2g1, c1 ----------------
__global__ __launch_bounds__(256) void k_prep_gemm(
    const float* __restrict__ wq, const float* __restrict__ wk,
    const float* __restrict__ g1, const float* __restrict__ W2,
    const float* __restrict__ b2d, const float* __restrict__ gb1,
    unsigned short* __restrict__ tmpWq, unsigned short* __restrict__ tmpWk,
    unsigned short* __restrict__ BposT, float* __restrict__ c1){
  int c = threadIdx.x, bid = blockIdx.x;
  if (bid < 256){
    int d = bid; float acc = 0.f;
    for (int e=0;e<256;e++) acc += wq[d*256+e]*g1[e*256+c];
    tmpWq[c*256 + d] = f2bf(acc);
  } else if (bid < 512){
    int d = bid-256; float acc = 0.f;
    for (int e=0;e<256;e++) acc += wk[d*256+e]*g1[e*256+c];
    tmpWk[c*256 + d] = f2bf(acc);
  } else if (bid < 768){
    int d = bid-512; float acc = 0.f;
    for (int e=0;e<256;e++) acc += W2[d*256+e]*g1[e*256+c];
    BposT[c*256 + d] = f2bf(acc);
  } else {
    float acc = 0.f;
    for (int e=0;e<256;e++) acc += b2d[e]*g1[e*256+c];
    c1[c] = acc + gb1[c];
  }
}

// ---------------- prep stage 2: fold fc1 into QKV ----------------
__global__ __launch_bounds__(256) void k_prep_gemm2(
    const float* __restrict__ fc1w, const float* __restrict__ fc1b,
    const float* __restrict__ wv,
    const unsigned short* __restrict__ tmpWq, const unsigned short* __restrict__ tmpWk,
    unsigned short* __restrict__ qkv2T, float* __restrict__ cvec){
  int c = threadIdx.x, bid = blockIdx.x;
  if (bid < 256){
    int d = bid; float acc = 0.f;
    for (int e=0;e<256;e++) acc += fc1w[d*256+e]*bf2f(tmpWq[c*256+e]);
    qkv2T[c*256 + d] = f2bf(acc);
  } else if (bid < 512){
    int d = bid-256; float acc = 0.f;
    for (int e=0;e<256;e++) acc += fc1w[d*256+e]*bf2f(tmpWk[c*256+e]);
    qkv2T[(256+c)*256 + d] = f2bf(acc);
  } else if (bid < 768){
    int d = bid-512; float acc = 0.f;
    for (int e=0;e<256;e++) acc += fc1w[d*256+e]*wv[e*256+c];
    qkv2T[(512+c)*256 + d] = f2bf(acc);
  } else {
    float aq=0.f, ak=0.f, av=0.f;
    for (int e=0;e<256;e++){
      float fb = fc1b[e];
      aq += fb*bf2f(tmpWq[c*256+e]);
      ak += fb*bf2f(tmpWk[c*256+e]);
      av += fb*wv[e*256+c];
    }
    cvec[c] = aq; cvec[256+c] = ak; cvec[512+c] = av;
  }
}

// ======== kNN via exact radix rank-select: one wave/point, 3 passes ========
// monotone float->uint mapping: a<b  <=>  map(a)<map(b) (unsigned)
__device__ __forceinline__ u32 fmap(float d){
  u32 u = __builtin_bit_cast(u32, d);
  return ((int)u < 0) ? ~u : (u | 0x80000000u);
}

// find first bin e with cum(<=e) >= need over 256-bin LDS histogram; c = cum(<e)
__device__ __forceinline__ void find_thresh(const int* hist, int lane, int need,
                                            int* e_out, int* c_out){
  int h0 = hist[lane*4], h1 = hist[lane*4+1], h2 = hist[lane*4+2], h3 = hist[lane*4+3];
  int ps = h0 + h1 + h2 + h3;
  int incl = ps;
  #pragma unroll
  for (int d = 1; d < 64; d <<= 1){
    int tv = __shfl_up(incl, d, 64);
    if (lane >= d) incl += tv;
  }
  int excl = incl - ps;
  int b0 = excl, b1 = excl + h0, b2 = b1 + h1, b3 = b2 + h2;
  bool f0 = (b0 < need) && (b0 + h0 >= need);
  bool f1 = (b1 < need) && (b1 + h1 >= need);
  bool f2 = (b2 < need) && (b2 + h2 >= need);
  bool f3 = (b3 < need) && (b3 + h3 >= need);
  int e_loc = f0 ? lane*4 : f1 ? lane*4+1 : f2 ? lane*4+2 : lane*4+3;
  int c_loc = f0 ? b0 : f1 ? b1 : f2 ? b2 : b3;
  u64 mk = __ballot(f0 | f1 | f2 | f3);
  int wl = __ffsll(mk) - 1;
  *e_out = __shfl(e_loc, wl, 64);
  *c_out = __shfl(c_loc, wl, 64);
}

__global__ __launch_bounds__(256) void k_knn(const float4* __restrict__ xyzw,
                                             int* __restrict__ gidxbuf,
                                             float4* __restrict__ relbuf){
  __shared__ int histA[4][256];
  __shared__ int histB[4][256];
  __shared__ u32 lstU[4][64];
  __shared__ int lstM[4][64];

  int t = threadIdx.x, lane = t & 63, wv = t >> 6;
  int widx = blockIdx.x * 4 + wv;          // 0..16383
  int b = widx >> 12, n = widx & 4095;
  const float4* xb = xyzw + (size_t)b * NPTS;
  float4 P = xb[n];
  float x2n = P.w;
  int* hA = histA[wv]; int* hB = histB[wv];

  #pragma unroll
  for (int j = 0; j < 4; j++){ hA[lane*4+j] = 0; hB[lane*4+j] = 0; }
  wfence();

  // pass 1: coarse histogram (top 8 bits of mapped distance)
  for (int it = 0; it < 64; it++){
    float4 Q = xb[it*64 + lane];
    float dot = P.x*Q.x + P.y*Q.y + P.z*Q.z;
    u32 u = fmap(x2n + Q.w - 2.0f*dot);
    atomicAdd(&hA[u >> 24], 1);
  }
  wfence();
  int e1, c0;
  find_thresh(hA, lane, 16, &e1, &c0);

  // pass 2: refine within bin e1 (next 8 bits)
  for (int it = 0; it < 64; it++){
    float4 Q = xb[it*64 + lane];
    float dot = P.x*Q.x + P.y*Q.y + P.z*Q.z;
    u32 u = fmap(x2n + Q.w - 2.0f*dot);
    if ((int)(u >> 24) == e1) atomicAdd(&hB[(u >> 16) & 0xFF], 1);
  }
  wfence();
  int m1, cc;
  find_thresh(hB, lane, 16 - c0, &m1, &cc);
  int c1 = c0 + cc;                        // definite members, < 16

  // pass 3: emit definite members; stash boundary sub-bin members
  int base = 0, Lc = 0;
  size_t orow = (size_t)widx * 16;
  for (int it = 0; it < 64; it++){
    int m = it*64 + lane;
    float4 Q = xb[m];
    float dot = P.x*Q.x + P.y*Q.y + P.z*Q.z;
    u32 u = fmap(x2n + Q.w - 2.0f*dot);
    int hi = u >> 24, mid = (u >> 16) & 0xFF;
    bool def = (hi < e1) || (hi == e1 && mid < m1);
    bool bnd = (hi == e1) && (mid == m1);
    u64 mkd = __ballot(def);
    if (def){
      int slot = base + __popcll(mkd & ((1ULL << lane) - 1ULL));
      gidxbuf[orow + slot] = b*NPTS + m;
      relbuf[orow + slot]  = make_float4(P.x - Q.x, P.y - Q.y, P.z - Q.z, 0.f);
    }
    base += __popcll(mkd);
    u64 mkb = __ballot(bnd);
    if (bnd){
      int sl = Lc + __popcll(mkb & ((1ULL << lane) - 1ULL));
      if (sl < 64){ lstU[wv][sl] = u; lstM[wv][sl] = m; }
    }
    Lc += __popcll(mkb);
  }
  wfence();
  if (Lc > 64) Lc = 64;

  // pop the remaining 16-c1 smallest (u, idx) lexicographically (== top_k tie-break)
  int r2 = 16 - c1;
  u32 lu = (lane < Lc) ? lstU[wv][lane] : 0xFFFFFFFFu;
  int lm = (lane < Lc) ? lstM[wv][lane] : 0x7FFFFFFF;
  bool popped = false;
  for (int r = 0; r < r2; r++){
    u32 ku = popped ? 0xFFFFFFFFu : lu;
    int km = popped ? 0x7FFFFFFF : lm;
    #pragma unroll
    for (int off = 32; off >= 1; off >>= 1){
      u32 ou = __shfl_xor(ku, off, 64);
      int om = __shfl_xor(km, off, 64);
      if (ou < ku || (ou == ku && om < km)){ ku = ou; km = om; }
    }
    bool mine = !popped && (lane < Lc) && (lu == ku) && (lm == km);
    u64 mk = __ballot(mine);
    int wl = __ffsll(mk) - 1;
    if (lane == wl){
      popped = true;
      float4 Q = xb[km];
      gidxbuf[orow + c1 + r] = b*NPTS + km;
      relbuf[orow + c1 + r]  = make_float4(P.x - Q.x, P.y - Q.y, P.z - Q.z, 0.f);
    }
  }
}

// ================= unified m97-style GEMM: 128x128 tile, BK=32, global_load_lds =======
// MODE 0: QKV  A=Xb(16384x256)  BT=qkv2T N=1024 -> qg|kg|v|sc (+cvec)
// MODE 2: G2   A=on-the-fly H   BT=BposT N=512  -> a1 (relu(posg+qg-kg+c1)), vpe (pe+b2+v)
// MODE 3: G3   A=a1             BT=g2sT  N=256  -> softmax+combine(vpe) -> res
// MODE 4: FIN  A=res            BT=fc2T  N=256  -> fp32 out (+fc2b+sc)
template<int MODE>
__global__ __launch_bounds__(256) void k_mm(
    const unsigned short* __restrict__ A, const unsigned short* __restrict__ BT,
    int rowbase,
    const float* __restrict__ bias, const float* __restrict__ b2v,
    const unsigned short* __restrict__ qg, const unsigned short* __restrict__ kg,
    const unsigned short* __restrict__ vb,
    const float4* __restrict__ relbuf, const int* __restrict__ gidxbuf,
    const float* __restrict__ W1, const float* __restrict__ b1d,
    unsigned short* __restrict__ o0, unsigned short* __restrict__ o1,
    unsigned short* __restrict__ o2, unsigned short* __restrict__ o3,
    const unsigned short* __restrict__ vper,
    float* __restrict__ fout){
  __shared__ unsigned short As[4096];   // 128 x 32 linear
  __shared__ unsigned short Bs[4096];
  __shared__ float  W1s[768];
  __shared__ float  b1s[256];
  __shared__ float4 relS[128];
  __shared__ int    gidxS[128];

  int t = threadIdx.x;
  int lane = t & 63, w = t >> 6, wm = w >> 1, wn = w & 1;
  int lrow = lane & 15, lkg = lane >> 4;
  int m0 = blockIdx.x * 128, n0 = blockIdx.y * 128;

  if constexpr (MODE == 2){
    if (t < 128){
      relS[t]  = relbuf[(size_t)rowbase + m0 + t];
      gidxS[t] = gidxbuf[(size_t)rowbase + m0 + t];
    }
    for (int i = t; i < 768; i += 256) W1s[i] = W1[i];
    b1s[t] = b1d[t];
    __syncthreads();
  }

  int sr = t >> 2, sc = (t & 3) * 8;               // staging: row, col(8 bf16=16B)
  unsigned short* lA = As + (w << 9);              // wave-uniform LDS base (1KB/wave)
  unsigned short* lB = Bs + (w << 9);
  const unsigned short* gB = BT + (size_t)(n0 + sr)*256 + sc;

  f32x4 acc[4][4] = {};
  for (int k0 = 0; k0 < 256; k0 += 32){
    if constexpr (MODE == 2){
      // compute H tile rows [m0,m0+128) cols [k0,k0+32) in-place
      int r = t >> 1, h = (t & 1) << 4;
      float4 rl = relS[r];
      bf16x8 h0, h1;
      #pragma unroll
      for (int j = 0; j < 8; j++){
        int c = k0 + h + j;
        float x0 = rl.x*W1s[c]   + rl.y*W1s[256+c]   + rl.z*W1s[512+c]   + b1s[c];
        float x1 = rl.x*W1s[c+8] + rl.y*W1s[256+c+8] + rl.z*W1s[512+c+8] + b1s[c+8];
        h0[j] = (short)f2bf(fmaxf(x0, 0.f));
        h1[j] = (short)f2bf(fmaxf(x1, 0.f));
      }
      *(bf16x8*)&As[r*32 + h]     = h0;
      *(bf16x8*)&As[r*32 + h + 8] = h1;
    } else {
      const unsigned short* gA = A + (size_t)(m0 + sr)*256 + k0 + sc;
      gl_lds16(gA,          lA);
      gl_lds16(gA + 64*256, lA + 2048);
    }
    gl_lds16(gB + k0,          lB);
    gl_lds16(gB + k0 + 64*256, lB + 2048);
    __syncthreads();
    bf16x8 af[4], bfr[4];
    #pragma unroll
    for (int fi = 0; fi < 4; fi++)
      af[fi] = *(const bf16x8*)&As[(wm*64 + fi*16 + lrow)*32 + lkg*8];
    #pragma unroll
    for (int nf = 0; nf < 4; nf++)
      bfr[nf] = *(const bf16x8*)&Bs[(wn*64 + nf*16 + lrow)*32 + lkg*8];
    #pragma unroll
    for (int fi = 0; fi < 4; fi++)
      #pragma unroll
      for (int nf = 0; nf < 4; nf++)
        acc[fi][nf] = MFMA(af[fi], bfr[nf], acc[fi][nf]);
    __syncthreads();
  }

  if constexpr (MODE == 0){
    #pragma unroll
    for (int fi=0; fi<4; fi++)
      #pragma unroll
      for (int nf=0; nf<4; nf++)
        #pragma unroll
        for (int r=0;r<4;r++){
          int row = m0 + wm*64 + fi*16 + lkg*4 + r;
          int col = n0 + wn*64 + nf*16 + lrow;
          float v = acc[fi][nf][r] + bias[col];
          int sel = col >> 8, cc = col & 255;
          unsigned short* op = (sel==0)?o0:(sel==1)?o1:(sel==2)?o2:o3;
          op[(size_t)row*256 + cc] = f2bf(v);
        }
  } else if constexpr (MODE == 2){
    #pragma unroll
    for (int fi=0; fi<4; fi++){
      int g = (rowbase + m0 + wm*64 + fi*16) >> 4;     // point id (16 rows = 1 point)
      #pragma unroll
      for (int nf=0; nf<4; nf++){
        int colg = n0 + wn*64 + nf*16 + lrow;          // 0..511
        if (colg < 256){
          float qv = bf2f(qg[(size_t)g*256 + colg]) + bias[colg];   // bias = c1
          #pragma unroll
          for (int r=0;r<4;r++){
            int rl_ = wm*64 + fi*16 + lkg*4 + r;
            int gi = gidxS[rl_];
            float a1 = acc[fi][nf][r] + qv - bf2f(kg[(size_t)gi*256 + colg]);
            o0[(size_t)(m0 + rl_)*256 + colg] = f2bf(fmaxf(a1, 0.f));
          }
        } else {
          int c2 = colg - 256;
          float bb = b2v[c2];
          #pragma unroll
          for (int r=0;r<4;r++){
            int rl_ = wm*64 + fi*16 + lkg*4 + r;
            int gi = gidxS[rl_];
            float vpe = acc[fi][nf][r] + bb + bf2f(vb[(size_t)gi*256 + c2]);
            o1[(size_t)(m0 + rl_)*256 + c2] = f2bf(vpe);
          }
        }
      }
    }
  } else if constexpr (MODE == 3){
    #pragma unroll
    for (int fi=0; fi<4; fi++){
      int g = (rowbase + m0 + wm*64 + fi*16) >> 4;
      #pragma unroll
      for (int nf=0; nf<4; nf++){
        int colg = n0 + wn*64 + nf*16 + lrow;          // 0..255
        float s[4], e[4];
        #pragma unroll
        for (int r=0;r<4;r++) s[r] = acc[fi][nf][r] + bias[colg]*0.0625f;  // bias = gb2
        float mx = fmaxf(fmaxf(s[0],s[1]), fmaxf(s[2],s[3]));
        mx = fmaxf(mx, __shfl_xor(mx,16,64));
        mx = fmaxf(mx, __shfl_xor(mx,32,64));
        float sm = 0.f;
        #pragma unroll
        for (int r=0;r<4;r++){ e[r] = __expf(s[r]-mx); sm += e[r]; }
        sm += __shfl_xor(sm,16,64);
        sm += __shfl_xor(sm,32,64);
        float rs = 1.f/sm, tsum = 0.f;
        #pragma unroll
        for (int r=0;r<4;r++){
          int rl_ = wm*64 + fi*16 + lkg*4 + r;
          tsum += (e[r]*rs) * bf2f(vper[(size_t)(m0 + rl_)*256 + colg]);
        }
        tsum += __shfl_xor(tsum,16,64);
        tsum += __shfl_xor(tsum,32,64);
        if (lkg == 0) o0[(size_t)g*256 + colg] = f2bf(tsum);
      }
    }
  } else {   // FIN
    #pragma unroll
    for (int fi=0; fi<4; fi++)
      #pragma unroll
      for (int nf=0; nf<4; nf++)
        #pragma unroll
        for (int r=0;r<4;r++){
          int row = m0 + wm*64 + fi*16 + lkg*4 + r;
          int col = n0 + wn*64 + nf*16 + lrow;
          fout[(size_t)row*256 + col] = acc[fi][nf][r] + bias[col]
                                      + bf2f(qg[(size_t)row*256 + col]);  // qg slot = scbuf
        }
  }
}

// ---------------- host ----------------
extern "C" void kernel_launch(void* const* d_in, const int* in_sizes, int n_in,
                              void* d_out, int out_size, void* d_ws, size_t ws_size,
                              hipStream_t stream){
  (void)in_sizes; (void)n_in; (void)out_size;
  const float* xyz  = (const float*)d_in[0];
  const float* feat = (const float*)d_in[1];
  const float* W1   = (const float*)d_in[2];
  const float* b1d  = (const float*)d_in[3];
  const float* W2   = (const float*)d_in[4];
  const float* b2d  = (const float*)d_in[5];
  const float* fc1w = (const float*)d_in[6];
  const float* fc1b = (const float*)d_in[7];
  const float* wq   = (const float*)d_in[8];
  const float* wk   = (const float*)d_in[9];
  const float* wv   = (const float*)d_in[10];
  const float* g1   = (const float*)d_in[11];
  const float* gb1  = (const float*)d_in[12];
  const float* g2   = (const float*)d_in[13];
  const float* gb2  = (const float*)d_in[14];
  const float* fc2w = (const float*)d_in[15];
  const float* fc2b = (const float*)d_in[16];
  const float* scw  = (const float*)d_in[17];
  const float* scb  = (const float*)d_in[18];

  char* ws = (char*)d_ws;
  size_t off = 0;
  auto alloc = [&](size_t bytes)->void*{ void* p = ws + off; off += (bytes + 255) & ~(size_t)255; return p; };
  unsigned short* Xb     = (unsigned short*)alloc((size_t)NTOT*256*2);  // reused as res
  unsigned short* qgb    = (unsigned short*)alloc((size_t)NTOT*256*2);
  unsigned short* kgb    = (unsigned short*)alloc((size_t)NTOT*256*2);
  unsigned short* vbb    = (unsigned short*)alloc((size_t)NTOT*256*2);
  unsigned short* scbuf  = (unsigned short*)alloc((size_t)NTOT*256*2);
  int*            gidxbuf= (int*)alloc((size_t)NROWS*4);
  float4*         relbuf = (float4*)alloc((size_t)NROWS*16);
  float4*         xyzw   = (float4*)alloc((size_t)NTOT*16);
  unsigned short* qkv2T  = (unsigned short*)alloc(1024*256*2);
  unsigned short* tmpWq  = (unsigned short*)alloc(256*256*2);
  unsigned short* tmpWk  = (unsigned short*)alloc(256*256*2);
  unsigned short* BposT  = (unsigned short*)alloc(512*256*2);
  unsigned short* g2sT   = (unsigned short*)alloc(256*256*2);
  unsigned short* fc2T   = (unsigned short*)alloc(256*256*2);
  float*          c1     = (float*)alloc(256*4);
  float*          cvec   = (float*)alloc(1024*4);
  unsigned short* res    = Xb;

  // adaptive chunk: a1 + vpe cost CR*1024 bytes
  int CR = NROWS;
  while (CR > 16384 && off + (size_t)CR*1024 > ws_size) CR >>= 1;
  unsigned short* a1buf  = (unsigned short*)alloc((size_t)CR*256*2);
  unsigned short* vpebuf = (unsigned short*)alloc((size_t)CR*256*2);

  k_convert<<<4096, 256, 0, stream>>>(feat, Xb, NTOT*256);
  k_xyzw<<<64, 256, 0, stream>>>(xyz, xyzw);
  k_prep_mats<<<256, 256, 0, stream>>>(scw, g2, fc2w, W2, scb, qkv2T, g2sT, fc2T, BposT, cvec);
  k_prep_gemm<<<769, 256, 0, stream>>>(wq, wk, g1, W2, b2d, gb1, tmpWq, tmpWk, BposT, c1);
  k_prep_gemm2<<<769, 256, 0, stream>>>(fc1w, fc1b, wv, tmpWq, tmpWk, qkv2T, cvec);
  k_knn<<<4096, 256, 0, stream>>>(xyzw, gidxbuf, relbuf);

  k_mm<0><<<dim3(128, 8), 256, 0, stream>>>(Xb, qkv2T, 0, cvec, nullptr,
      nullptr, nullptr, nullptr, nullptr, nullptr, nullptr, nullptr,
      qgb, kgb, vbb, scbuf, nullptr, nullptr);

  for (int c0 = 0; c0 < NROWS; c0 += CR){
    k_mm<2><<<dim3(CR/128, 4), 256, 0, stream>>>(nullptr, BposT, c0, c1, b2d,
        qgb, kgb, vbb, relbuf, gidxbuf, W1, b1d,
        a1buf, vpebuf, nullptr, nullptr, nullptr, nullptr);
    k_mm<3><<<dim3(CR/128, 2), 256, 0, stream>>>(a1buf, g2sT, c0, gb2, nullptr,
        nullptr, nullptr, nullptr, nullptr, nullptr, nullptr, nullptr,
        res, nullptr, nullptr, nullptr, vpebuf, nullptr);
  }

  k_mm<4><<<dim3(128, 2), 256, 0, stream>>>(res, fc2T, 0, fc2b, nullptr,
      scbuf, nullptr, nullptr, nullptr, nullptr, nullptr, nullptr,
      nullptr, nullptr, nullptr, nullptr, nullptr, (float*)d_out);
}

// Round 7
// 557.294 us; speedup vs baseline: 1.4473x; 1.0818x over previous
//
#include <hip/hip_runtime.h>
#include <hip/hip_bf16.h>
#include <math.h>

typedef __attribute__((ext_vector_type(8))) short bf16x8;
typedef __attribute__((ext_vector_type(4))) float f32x4;
typedef __attribute__((ext_vector_type(4))) short s16x4;
typedef unsigned int u32;
typedef unsigned long long u64;

#define NBATCH 4
#define NPTS   4096
#define NTOT   (NBATCH*NPTS)     // 16384 points
#define NROWS  (NTOT*16)         // 262144 (point,neighbor) rows

__device__ __forceinline__ float bf2f(unsigned short h){
  unsigned int u = ((unsigned int)h) << 16;
  return __builtin_bit_cast(float, u);
}
__device__ __forceinline__ unsigned short f2bf(float f){
  unsigned int u = __builtin_bit_cast(unsigned int, f);
  u += 0x7FFFu + ((u >> 16) & 1u);   // RNE
  return (unsigned short)(u >> 16);
}
__device__ __forceinline__ unsigned short f2bfh(float f){   // HW cvt (RNE, pairs fuse to cvt_pk)
  return __bfloat16_as_ushort(__float2bfloat16(f));
}

#define MFMA(a,b,c) __builtin_amdgcn_mfma_f32_16x16x32_bf16((a),(b),(c),0,0,0)

typedef u32 __attribute__((address_space(1))) gas_u32;
typedef u32 __attribute__((address_space(3))) las_u32;
__device__ __forceinline__ void gl_lds16(const void* g, void* l){
  __builtin_amdgcn_global_load_lds((const gas_u32*)g, (las_u32*)l, 16, 0, 0);
}

// wave-internal LDS ordering fence (rule #18 pattern)
__device__ __forceinline__ void wfence(){
  asm volatile("s_waitcnt lgkmcnt(0)" ::: "memory");
  __builtin_amdgcn_sched_barrier(0);
}

// ---------------- prep: features -> bf16 ----------------
__global__ __launch_bounds__(256) void k_convert(const float* __restrict__ x,
                                                 unsigned short* __restrict__ xb, int n){
  int i = (blockIdx.x * 256 + threadIdx.x) * 4;
  if (i < n){
    float4 v = *(const float4*)(x + i);
    s16x4 o;
    o[0] = (short)f2bf(v.x); o[1] = (short)f2bf(v.y);
    o[2] = (short)f2bf(v.z); o[3] = (short)f2bf(v.w);
    *(s16x4*)(xb + i) = o;
  }
}

// ---------------- prep: xyz -> float4 (x,y,z,|p|^2) ----------------
__global__ __launch_bounds__(256) void k_xyzw(const float* __restrict__ xyz,
                                              float4* __restrict__ xyzw){
  int i = blockIdx.x * 256 + threadIdx.x;   // 16384
  float x = xyz[i*3], y = xyz[i*3+1], z = xyz[i*3+2];
  xyzw[i] = make_float4(x, y, z, x*x + y*y + z*z);
}

// ---------------- prep: transposed bf16 weight copies ----------------
__global__ __launch_bounds__(256) void k_prep_mats(
    const float* __restrict__ scw, const float* __restrict__ g2,
    const float* __restrict__ fc2, const float* __restrict__ W2,
    const float* __restrict__ scb,
    unsigned short* __restrict__ qkv2T, unsigned short* __restrict__ g2sT,
    unsigned short* __restrict__ fc2T, unsigned short* __restrict__ BposT,
    float* __restrict__ cvec){
  int c = blockIdx.x, d = threadIdx.x;
  qkv2T[(768+c)*256 + d] = f2bf(scw[d*256 + c]);             // sc^T
  g2sT[c*256 + d]        = f2bf(g2[d*256 + c] * 0.0625f);    // fold 1/sqrt(DM)=1/16
  fc2T[c*256 + d]        = f2bf(fc2[d*256 + c]);
  BposT[(256+c)*256 + d] = f2bf(W2[d*256 + c]);              // W2^T (pe)
  if (d == 0) cvec[768 + c] = scb[c];
}

// ---------------- prep stage 1: Wqg = wq@g1, Wkg = wk@g1, W2g1, c1 ----------------
__global__ __launch_bounds__(256) void k_prep_gemm(
    const float* __restrict__ wq, const float* __restrict__ wk,
    const float* __restrict__ g1, const float* __restrict__ W2,
    const float* __restrict__ b2d, const float* __restrict__ gb1,
    unsigned short* __restrict__ tmpWq, unsigned short* __restrict__ tmpWk,
    unsigned short* __restrict__ BposT, float* __restrict__ c1){
  int c = threadIdx.x, bid = blockIdx.x;
  if (bid < 256){
    int d = bid; float acc = 0.f;
    for (int e=0;e<256;e++) acc += wq[d*256+e]*g1[e*256+c];
    tmpWq[c*256 + d] = f2bf(acc);
  } else if (bid < 512){
    int d = bid-256; float acc = 0.f;
    for (int e=0;e<256;e++) acc += wk[d*256+e]*g1[e*256+c];
    tmpWk[c*256 + d] = f2bf(acc);
  } else if (bid < 768){
    int d = bid-512; float acc = 0.f;
    for (int e=0;e<256;e++) acc += W2[d*256+e]*g1[e*256+c];
    BposT[c*256 + d] = f2bf(acc);
  } else {
    float acc = 0.f;
    for (int e=0;e<256;e++) acc += b2d[e]*g1[e*256+c];
    c1[c] = acc + gb1[c];
  }
}

// ---------------- prep stage 2: fold fc1 into QKV ----------------
__global__ __launch_bounds__(256) void k_prep_gemm2(
    const float* __restrict__ fc1w, const float* __restrict__ fc1b,
    const float* __restrict__ wv,
    const unsigned short* __restrict__ tmpWq, const unsigned short* __restrict__ tmpWk,
    unsigned short* __restrict__ qkv2T, float* __restrict__ cvec){
  int c = threadIdx.x, bid = blockIdx.x;
  if (bid < 256){
    int d = bid; float acc = 0.f;
    for (int e=0;e<256;e++) acc += fc1w[d*256+e]*bf2f(tmpWq[c*256+e]);
    qkv2T[c*256 + d] = f2bf(acc);
  } else if (bid < 512){
    int d = bid-256; float acc = 0.f;
    for (int e=0;e<256;e++) acc += fc1w[d*256+e]*bf2f(tmpWk[c*256+e]);
    qkv2T[(256+c)*256 + d] = f2bf(acc);
  } else if (bid < 768){
    int d = bid-512; float acc = 0.f;
    for (int e=0;e<256;e++) acc += fc1w[d*256+e]*wv[e*256+c];
    qkv2T[(512+c)*256 + d] = f2bf(acc);
  } else {
    float aq=0.f, ak=0.f, av=0.f;
    for (int e=0;e<256;e++){
      float fb = fc1b[e];
      aq += fb*bf2f(tmpWq[c*256+e]);
      ak += fb*bf2f(tmpWk[c*256+e]);
      av += fb*wv[e*256+c];
    }
    cvec[c] = aq; cvec[256+c] = ak; cvec[512+c] = av;
  }
}

// ======== kNN via exact radix rank-select: one wave/point, 3 passes ========
// monotone float->uint mapping: a<b  <=>  map(a)<map(b) (unsigned)
__device__ __forceinline__ u32 fmap(float d){
  u32 u = __builtin_bit_cast(u32, d);
  return ((int)u < 0) ? ~u : (u | 0x80000000u);
}

// threshold over a single-copy 256-bin histogram
__device__ __forceinline__ void find_thresh(const int* hist, int lane, int need,
                                            int* e_out, int* c_out){
  int h0 = hist[lane*4], h1 = hist[lane*4+1], h2 = hist[lane*4+2], h3 = hist[lane*4+3];
  int ps = h0 + h1 + h2 + h3;
  int incl = ps;
  #pragma unroll
  for (int d = 1; d < 64; d <<= 1){
    int tv = __shfl_up(incl, d, 64);
    if (lane >= d) incl += tv;
  }
  int excl = incl - ps;
  int b0 = excl, b1 = excl + h0, b2 = b1 + h1, b3 = b2 + h2;
  bool f0 = (b0 < need) && (b0 + h0 >= need);
  bool f1 = (b1 < need) && (b1 + h1 >= need);
  bool f2 = (b2 < need) && (b2 + h2 >= need);
  bool f3 = (b3 < need) && (b3 + h3 >= need);
  int e_loc = f0 ? lane*4 : f1 ? lane*4+1 : f2 ? lane*4+2 : lane*4+3;
  int c_loc = f0 ? b0 : f1 ? b1 : f2 ? b2 : b3;
  u64 mk = __ballot(f0 | f1 | f2 | f3);
  int wl = __ffsll(mk) - 1;
  *e_out = __shfl(e_loc, wl, 64);
  *c_out = __shfl(c_loc, wl, 64);
}

// threshold over 4 bank-rotated sub-copies (copy s: bin stored at s*256 + ((bin+s*8)&255))
__device__ __forceinline__ void find_thresh4(const int* hA, int lane, int need,
                                             int* e_out, int* c_out){
  int h[4];
  #pragma unroll
  for (int j=0;j<4;j++){
    int bin = lane*4+j;
    h[j] = hA[bin]
         + hA[256 + ((bin+8)&255)]
         + hA[512 + ((bin+16)&255)]
         + hA[768 + ((bin+24)&255)];
  }
  int ps = h[0] + h[1] + h[2] + h[3];
  int incl = ps;
  #pragma unroll
  for (int d = 1; d < 64; d <<= 1){
    int tv = __shfl_up(incl, d, 64);
    if (lane >= d) incl += tv;
  }
  int excl = incl - ps;
  int b0 = excl, b1 = excl + h[0], b2 = b1 + h[1], b3 = b2 + h[2];
  bool f0 = (b0 < need) && (b0 + h[0] >= need);
  bool f1 = (b1 < need) && (b1 + h[1] >= need);
  bool f2 = (b2 < need) && (b2 + h[2] >= need);
  bool f3 = (b3 < need) && (b3 + h[3] >= need);
  int e_loc = f0 ? lane*4 : f1 ? lane*4+1 : f2 ? lane*4+2 : lane*4+3;
  int c_loc = f0 ? b0 : f1 ? b1 : f2 ? b2 : b3;
  u64 mk = __ballot(f0 | f1 | f2 | f3);
  int wl = __ffsll(mk) - 1;
  *e_out = __shfl(e_loc, wl, 64);
  *c_out = __shfl(c_loc, wl, 64);
}

__global__ __launch_bounds__(256) void k_knn(const float4* __restrict__ xyzw,
                                             int* __restrict__ gidxbuf,
                                             float4* __restrict__ relbuf){
  __shared__ int histA[4][1024];    // 4 waves x 4 rotated copies x 256 bins
  __shared__ int histB[4][256];
  __shared__ u32 lstU[4][64];
  __shared__ int lstM[4][64];

  int t = threadIdx.x, lane = t & 63, wv = t >> 6;
  int widx = blockIdx.x * 4 + wv;          // 0..16383
  int b = widx >> 12, n = widx & 4095;
  const float4* xb = xyzw + (size_t)b * NPTS;
  float4 P = xb[n];
  float x2n = P.w;
  int* hA = histA[wv]; int* hB = histB[wv];

  #pragma unroll
  for (int j = 0; j < 16; j++) hA[lane*16+j] = 0;
  #pragma unroll
  for (int j = 0; j < 4; j++)  hB[lane*4+j] = 0;
  wfence();

  int cp = lane >> 4;                      // sub-copy 0..3 (16 lanes each)
  int cpoff = cp*256, cprot = cp*8;

  // pass 1: coarse histogram (top 8 bits), 2-way unrolled, rotated copies
  for (int it = 0; it < 64; it += 2){
    float4 Q0 = xb[it*64 + lane];
    float4 Q1 = xb[it*64 + 64 + lane];
    float d0 = x2n + Q0.w - 2.0f*(P.x*Q0.x + P.y*Q0.y + P.z*Q0.z);
    float d1 = x2n + Q1.w - 2.0f*(P.x*Q1.x + P.y*Q1.y + P.z*Q1.z);
    int b0 = (int)(fmap(d0) >> 24), b1 = (int)(fmap(d1) >> 24);
    atomicAdd(&hA[cpoff + ((b0 + cprot)&255)], 1);
    atomicAdd(&hA[cpoff + ((b1 + cprot)&255)], 1);
  }
  wfence();
  int e1, c0;
  find_thresh4(hA, lane, 16, &e1, &c0);

  // pass 2: refine within bin e1 (next 8 bits) — few active lanes, single copy
  for (int it = 0; it < 64; it++){
    float4 Q = xb[it*64 + lane];
    u32 u = fmap(x2n + Q.w - 2.0f*(P.x*Q.x + P.y*Q.y + P.z*Q.z));
    if ((int)(u >> 24) == e1) atomicAdd(&hB[(u >> 16) & 0xFF], 1);
  }
  wfence();
  int m1, cc;
  find_thresh(hB, lane, 16 - c0, &m1, &cc);
  int c1 = c0 + cc;                        // definite members, < 16
  u32 T16 = ((u32)e1 << 8) | (u32)m1;

  // pass 3: emit definite members; stash boundary sub-bin members
  int base = 0, Lc = 0;
  size_t orow = (size_t)widx * 16;
  for (int it = 0; it < 64; it++){
    int m = it*64 + lane;
    float4 Q = xb[m];
    u32 u = fmap(x2n + Q.w - 2.0f*(P.x*Q.x + P.y*Q.y + P.z*Q.z));
    u32 u16_ = u >> 16;
    bool def = u16_ < T16;
    bool bnd = u16_ == T16;
    u64 mkd = __ballot(def);
    if (def){
      int slot = base + __popcll(mkd & ((1ULL << lane) - 1ULL));
      gidxbuf[orow + slot] = b*NPTS + m;
      relbuf[orow + slot]  = make_float4(P.x - Q.x, P.y - Q.y, P.z - Q.z, 0.f);
    }
    base += __popcll(mkd);
    u64 mkb = __ballot(bnd);
    if (bnd){
      int sl = Lc + __popcll(mkb & ((1ULL << lane) - 1ULL));
      if (sl < 64){ lstU[wv][sl] = u; lstM[wv][sl] = m; }
    }
    Lc += __popcll(mkb);
  }
  wfence();
  if (Lc > 64) Lc = 64;

  // pop the remaining 16-c1 smallest (u, idx) lexicographically (== top_k tie-break)
  int r2 = 16 - c1;
  u32 lu = (lane < Lc) ? lstU[wv][lane] : 0xFFFFFFFFu;
  int lm = (lane < Lc) ? lstM[wv][lane] : 0x7FFFFFFF;
  bool popped = false;
  for (int r = 0; r < r2; r++){
    u32 ku = popped ? 0xFFFFFFFFu : lu;
    int km = popped ? 0x7FFFFFFF : lm;
    #pragma unroll
    for (int off = 32; off >= 1; off >>= 1){
      u32 ou = __shfl_xor(ku, off, 64);
      int om = __shfl_xor(km, off, 64);
      if (ou < ku || (ou == ku && om < km)){ ku = ou; km = om; }
    }
    bool mine = !popped && (lane < Lc) && (lu == ku) && (lm == km);
    u64 mk = __ballot(mine);
    int wl = __ffsll(mk) - 1;
    if (lane == wl){
      popped = true;
      float4 Q = xb[km];
      gidxbuf[orow + c1 + r] = b*NPTS + km;
      relbuf[orow + c1 + r]  = make_float4(P.x - Q.x, P.y - Q.y, P.z - Q.z, 0.f);
    }
  }
}

// ================= unified m97-style GEMM: 128x128 tile, BK=32, global_load_lds =======
// MODE 0: QKV  A=Xb(16384x256)  BT=qkv2T N=1024 -> qg|kg|v|sc (+cvec)
// MODE 2: G2   A=on-the-fly H   BT=BposT N=512  -> a1 (relu(posg+qg-kg+c1)), vpe (pe+b2+v)
// MODE 3: G3   A=a1             BT=g2sT  N=256  -> softmax+combine(vpe) -> res
// MODE 4: FIN  A=res            BT=fc2T  N=256  -> fp32 out (+fc2b+sc)
template<int MODE>
__global__ __launch_bounds__(256) void k_mm(
    const unsigned short* __restrict__ A, const unsigned short* __restrict__ BT,
    int rowbase,
    const float* __restrict__ bias, const float* __restrict__ b2v,
    const unsigned short* __restrict__ qg, const unsigned short* __restrict__ kg,
    const unsigned short* __restrict__ vb,
    const float4* __restrict__ relbuf, const int* __restrict__ gidxbuf,
    const float* __restrict__ W1, const float* __restrict__ b1d,
    unsigned short* __restrict__ o0, unsigned short* __restrict__ o1,
    unsigned short* __restrict__ o2, unsigned short* __restrict__ o3,
    const unsigned short* __restrict__ vper,
    float* __restrict__ fout){
  __shared__ unsigned short As[4096];   // 128 x 32 linear
  __shared__ unsigned short Bs[4096];
  __shared__ float4 W1s4[256];          // (w1x,w1y,w1z,b1) per column
  __shared__ float4 relS[128];
  __shared__ int    gidxS[128];

  int t = threadIdx.x;
  int lane = t & 63, w = t >> 6, wm = w >> 1, wn = w & 1;
  int lrow = lane & 15, lkg = lane >> 4;
  int bx = blockIdx.x;
  if constexpr (MODE == 2){
    // XCD-aware swizzle (T1): contiguous tile chunk per XCD; gridDim.x % 8 == 0
    int gx = gridDim.x;
    bx = (bx & 7) * (gx >> 3) + (bx >> 3);
  }
  int m0 = bx * 128, n0 = blockIdx.y * 128;

  float4 rl0 = make_float4(0.f,0.f,0.f,0.f);
  if constexpr (MODE == 2){
    if (t < 128){
      relS[t]  = relbuf[(size_t)rowbase + m0 + t];
      gidxS[t] = gidxbuf[(size_t)rowbase + m0 + t];
    }
    W1s4[t] = make_float4(W1[t], W1[256+t], W1[512+t], b1d[t]);
    __syncthreads();
    rl0 = relS[t >> 1];                 // hoisted: loop-invariant across k0
  }

  int sr = t >> 2, sc = (t & 3) * 8;               // staging: row, col(8 bf16=16B)
  unsigned short* lA = As + (w << 9);              // wave-uniform LDS base (1KB/wave)
  unsigned short* lB = Bs + (w << 9);
  const unsigned short* gB = BT + (size_t)(n0 + sr)*256 + sc;

  f32x4 acc[4][4] = {};
  for (int k0 = 0; k0 < 256; k0 += 32){
    if constexpr (MODE == 2){
      // compute H tile rows [m0,m0+128) cols [k0,k0+32) on the fly
      int r = t >> 1, h = (t & 1) << 4;
      bf16x8 h0, h1;
      #pragma unroll
      for (int j = 0; j < 8; j++){
        int c = k0 + h + j;
        float4 wa = W1s4[c];
        float4 wb = W1s4[c+8];
        float x0 = rl0.x*wa.x + rl0.y*wa.y + rl0.z*wa.z + wa.w;
        float x1 = rl0.x*wb.x + rl0.y*wb.y + rl0.z*wb.z + wb.w;
        h0[j] = (short)f2bfh(fmaxf(x0, 0.f));
        h1[j] = (short)f2bfh(fmaxf(x1, 0.f));
      }
      *(bf16x8*)&As[r*32 + h]     = h0;
      *(bf16x8*)&As[r*32 + h + 8] = h1;
    } else {
      const unsigned short* gA = A + (size_t)(m0 + sr)*256 + k0 + sc;
      gl_lds16(gA,          lA);
      gl_lds16(gA + 64*256, lA + 2048);
    }
    gl_lds16(gB + k0,          lB);
    gl_lds16(gB + k0 + 64*256, lB + 2048);
    __syncthreads();
    bf16x8 af[4], bfr[4];
    #pragma unroll
    for (int fi = 0; fi < 4; fi++)
      af[fi] = *(const bf16x8*)&As[(wm*64 + fi*16 + lrow)*32 + lkg*8];
    #pragma unroll
    for (int nf = 0; nf < 4; nf++)
      bfr[nf] = *(const bf16x8*)&Bs[(wn*64 + nf*16 + lrow)*32 + lkg*8];
    #pragma unroll
    for (int fi = 0; fi < 4; fi++)
      #pragma unroll
      for (int nf = 0; nf < 4; nf++)
        acc[fi][nf] = MFMA(af[fi], bfr[nf], acc[fi][nf]);
    __syncthreads();
  }

  if constexpr (MODE == 0){
    #pragma unroll
    for (int fi=0; fi<4; fi++)
      #pragma unroll
      for (int nf=0; nf<4; nf++)
        #pragma unroll
        for (int r=0;r<4;r++){
          int row = m0 + wm*64 + fi*16 + lkg*4 + r;
          int col = n0 + wn*64 + nf*16 + lrow;
          float v = acc[fi][nf][r] + bias[col];
          int sel = col >> 8, cc = col & 255;
          unsigned short* op = (sel==0)?o0:(sel==1)?o1:(sel==2)?o2:o3;
          op[(size_t)row*256 + cc] = f2bf(v);
        }
  } else if constexpr (MODE == 2){
    #pragma unroll
    for (int fi=0; fi<4; fi++){
      int g = (rowbase + m0 + wm*64 + fi*16) >> 4;     // point id (16 rows = 1 point)
      #pragma unroll
      for (int nf=0; nf<4; nf++){
        int colg = n0 + wn*64 + nf*16 + lrow;          // 0..511
        if (colg < 256){
          float qv = bf2f(qg[(size_t)g*256 + colg]) + bias[colg];   // bias = c1
          #pragma unroll
          for (int r=0;r<4;r++){
            int rl_ = wm*64 + fi*16 + lkg*4 + r;
            int gi = gidxS[rl_];
            float a1 = acc[fi][nf][r] + qv - bf2f(kg[(size_t)gi*256 + colg]);
            o0[(size_t)(m0 + rl_)*256 + colg] = f2bfh(fmaxf(a1, 0.f));
          }
        } else {
          int c2 = colg - 256;
          float bb = b2v[c2];
          #pragma unroll
          for (int r=0;r<4;r++){
            int rl_ = wm*64 + fi*16 + lkg*4 + r;
            int gi = gidxS[rl_];
            float vpe = acc[fi][nf][r] + bb + bf2f(vb[(size_t)gi*256 + c2]);
            o1[(size_t)(m0 + rl_)*256 + c2] = f2bfh(vpe);
          }
        }
      }
    }
  } else if constexpr (MODE == 3){
    #pragma unroll
    for (int fi=0; fi<4; fi++){
      int g = (rowbase + m0 + wm*64 + fi*16) >> 4;
      #pragma unroll
      for (int nf=0; nf<4; nf++){
        int colg = n0 + wn*64 + nf*16 + lrow;          // 0..255
        float s[4], e[4];
        #pragma unroll
        for (int r=0;r<4;r++) s[r] = acc[fi][nf][r] + bias[colg]*0.0625f;  // bias = gb2
        float mx = fmaxf(fmaxf(s[0],s[1]), fmaxf(s[2],s[3]));
        mx = fmaxf(mx, __shfl_xor(mx,16,64));
        mx = fmaxf(mx, __shfl_xor(mx,32,64));
        float sm = 0.f;
        #pragma unroll
        for (int r=0;r<4;r++){ e[r] = __expf(s[r]-mx); sm += e[r]; }
        sm += __shfl_xor(sm,16,64);
        sm += __shfl_xor(sm,32,64);
        float rs = 1.f/sm, tsum = 0.f;
        #pragma unroll
        for (int r=0;r<4;r++){
          int rl_ = wm*64 + fi*16 + lkg*4 + r;
          tsum += (e[r]*rs) * bf2f(vper[(size_t)(m0 + rl_)*256 + colg]);
        }
        tsum += __shfl_xor(tsum,16,64);
        tsum += __shfl_xor(tsum,32,64);
        if (lkg == 0) o0[(size_t)g*256 + colg] = f2bf(tsum);
      }
    }
  } else {   // FIN
    #pragma unroll
    for (int fi=0; fi<4; fi++)
      #pragma unroll
      for (int nf=0; nf<4; nf++)
        #pragma unroll
        for (int r=0;r<4;r++){
          int row = m0 + wm*64 + fi*16 + lkg*4 + r;
          int col = n0 + wn*64 + nf*16 + lrow;
          fout[(size_t)row*256 + col] = acc[fi][nf][r] + bias[col]
                                      + bf2f(qg[(size_t)row*256 + col]);  // qg slot = scbuf
        }
  }
}

// ---------------- host ----------------
extern "C" void kernel_launch(void* const* d_in, const int* in_sizes, int n_in,
                              void* d_out, int out_size, void* d_ws, size_t ws_size,
                              hipStream_t stream){
  (void)in_sizes; (void)n_in; (void)out_size;
  const float* xyz  = (const float*)d_in[0];
  const float* feat = (const float*)d_in[1];
  const float* W1   = (const float*)d_in[2];
  const float* b1d  = (const float*)d_in[3];
  const float* W2   = (const float*)d_in[4];
  const float* b2d  = (const float*)d_in[5];
  const float* fc1w = (const float*)d_in[6];
  const float* fc1b = (const float*)d_in[7];
  const float* wq   = (const float*)d_in[8];
  const float* wk   = (const float*)d_in[9];
  const float* wv   = (const float*)d_in[10];
  const float* g1   = (const float*)d_in[11];
  const float* gb1  = (const float*)d_in[12];
  const float* g2   = (const float*)d_in[13];
  const float* gb2  = (const float*)d_in[14];
  const float* fc2w = (const float*)d_in[15];
  const float* fc2b = (const float*)d_in[16];
  const float* scw  = (const float*)d_in[17];
  const float* scb  = (const float*)d_in[18];

  char* ws = (char*)d_ws;
  size_t off = 0;
  auto alloc = [&](size_t bytes)->void*{ void* p = ws + off; off += (bytes + 255) & ~(size_t)255; return p; };
  unsigned short* Xb     = (unsigned short*)alloc((size_t)NTOT*256*2);  // reused as res
  unsigned short* qgb    = (unsigned short*)alloc((size_t)NTOT*256*2);
  unsigned short* kgb    = (unsigned short*)alloc((size_t)NTOT*256*2);
  unsigned short* vbb    = (unsigned short*)alloc((size_t)NTOT*256*2);
  unsigned short* scbuf  = (unsigned short*)alloc((size_t)NTOT*256*2);
  int*            gidxbuf= (int*)alloc((size_t)NROWS*4);
  float4*         relbuf = (float4*)alloc((size_t)NROWS*16);
  float4*         xyzw   = (float4*)alloc((size_t)NTOT*16);
  unsigned short* qkv2T  = (unsigned short*)alloc(1024*256*2);
  unsigned short* tmpWq  = (unsigned short*)alloc(256*256*2);
  unsigned short* tmpWk  = (unsigned short*)alloc(256*256*2);
  unsigned short* BposT  = (unsigned short*)alloc(512*256*2);
  unsigned short* g2sT   = (unsigned short*)alloc(256*256*2);
  unsigned short* fc2T   = (unsigned short*)alloc(256*256*2);
  float*          c1     = (float*)alloc(256*4);
  float*          cvec   = (float*)alloc(1024*4);
  unsigned short* res    = Xb;

  // adaptive chunk: a1 + vpe cost CR*1024 bytes
  int CR = NROWS;
  while (CR > 16384 && off + (size_t)CR*1024 > ws_size) CR >>= 1;
  unsigned short* a1buf  = (unsigned short*)alloc((size_t)CR*256*2);
  unsigned short* vpebuf = (unsigned short*)alloc((size_t)CR*256*2);

  k_convert<<<4096, 256, 0, stream>>>(feat, Xb, NTOT*256);
  k_xyzw<<<64, 256, 0, stream>>>(xyz, xyzw);
  k_prep_mats<<<256, 256, 0, stream>>>(scw, g2, fc2w, W2, scb, qkv2T, g2sT, fc2T, BposT, cvec);
  k_prep_gemm<<<769, 256, 0, stream>>>(wq, wk, g1, W2, b2d, gb1, tmpWq, tmpWk, BposT, c1);
  k_prep_gemm2<<<769, 256, 0, stream>>>(fc1w, fc1b, wv, tmpWq, tmpWk, qkv2T, cvec);
  k_knn<<<4096, 256, 0, stream>>>(xyzw, gidxbuf, relbuf);

  k_mm<0><<<dim3(128, 8), 256, 0, stream>>>(Xb, qkv2T, 0, cvec, nullptr,
      nullptr, nullptr, nullptr, nullptr, nullptr, nullptr, nullptr,
      qgb, kgb, vbb, scbuf, nullptr, nullptr);

  for (int c0 = 0; c0 < NROWS; c0 += CR){
    k_mm<2><<<dim3(CR/128, 4), 256, 0, stream>>>(nullptr, BposT, c0, c1, b2d,
        qgb, kgb, vbb, relbuf, gidxbuf, W1, b1d,
        a1buf, vpebuf, nullptr, nullptr, nullptr, nullptr);
    k_mm<3><<<dim3(CR/128, 2), 256, 0, stream>>>(a1buf, g2sT, c0, gb2, nullptr,
        nullptr, nullptr, nullptr, nullptr, nullptr, nullptr, nullptr,
        res, nullptr, nullptr, nullptr, vpebuf, nullptr);
  }

  k_mm<4><<<dim3(128, 2), 256, 0, stream>>>(res, fc2T, 0, fc2b, nullptr,
      scbuf, nullptr, nullptr, nullptr, nullptr, nullptr, nullptr,
      nullptr, nullptr, nullptr, nullptr, nullptr, (float*)d_out);
}